// Round 12
// baseline (122.249 us; speedup 1.0000x reference)
//
#include <hip/hip_runtime.h>
#include <hip/hip_bf16.h>

// GNNRefiner: out = xyz + max_k( relu([x_i, x_j-x_i]·W1 + b1)·W2 + b2 )
// Factorization: e·W1 = x_i·(A-B) + x_j·B  with A=W1[0:387], B=W1[387:774].
// Pipeline: zero -> prep(fused,+hist) -> scan(+tile bounds) -> assign(x-sorted tiles)
//           -> knn (5-tile pass-1 T, pruned pass-2, exact fp32, orig-idx payload)
//           -> bf16 MFMA GEMM (+b1, Ub/Vb) -> final (dim-parallel, validated r11).
// KNN pruning: tile skipped iff gap^2 > T + 1e-3 with gap = x-gap to tile's bin-edge
// range; T = 16th-smallest of 64 disjoint-set lane minima (provable D16 upper bound).

#define N 8192
#define TD 384      // TOKEN_DIM
#define KNN 16
#define DX 387      // TD + 3
#define KP 416      // DX padded to multiple of 32
#define NF 768      // 2*TD output cols of fused GEMM
#define INFF __builtin_inff()

typedef __attribute__((ext_vector_type(8))) short short8;
typedef __attribute__((ext_vector_type(4))) float f32x4;
typedef __attribute__((ext_vector_type(2))) float f32x2;

// ---------------- packed fp32 helpers (bit-identical to scalar ops, 2 cands/instr) ----------------

__device__ __forceinline__ f32x2 pk_mul(f32x2 a, f32x2 b) {
    f32x2 r; asm("v_pk_mul_f32 %0, %1, %2" : "=v"(r) : "v"(a), "v"(b)); return r;
}
__device__ __forceinline__ f32x2 pk_add(f32x2 a, f32x2 b) {
    f32x2 r; asm("v_pk_add_f32 %0, %1, %2" : "=v"(r) : "v"(a), "v"(b)); return r;
}
__device__ __forceinline__ f32x2 pk_sub(f32x2 a, f32x2 b) {  // a - b, same rounding as fsub
    f32x2 r; asm("v_pk_add_f32 %0, %1, %2 neg_lo:[0,1] neg_hi:[0,1]" : "=v"(r) : "v"(a), "v"(b)); return r;
}
__device__ __forceinline__ f32x2 pk_fma(f32x2 a, f32x2 b, f32x2 c) {
    f32x2 r; asm("v_pk_fma_f32 %0, %1, %2, %3" : "=v"(r) : "v"(a), "v"(b), "v"(c)); return r;
}

// d2 = (qw + sq_j) - 2*dot, dot = fma(qz,z, fma(qy,y, mul(qx,x)))  [bit-identical to ref]
__device__ __forceinline__ void dist4(f32x2 qx, f32x2 qy, f32x2 qz, f32x2 qw,
                                      f32x2 x01, f32x2 x23, f32x2 y01, f32x2 y23,
                                      f32x2 z01, f32x2 z23, f32x2 s01, f32x2 s23,
                                      f32x2& d01, f32x2& d23) {
    f32x2 dot01 = pk_fma(qz, z01, pk_fma(qy, y01, pk_mul(qx, x01)));
    f32x2 dot23 = pk_fma(qz, z23, pk_fma(qy, y23, pk_mul(qx, x23)));
    d01 = pk_sub(pk_add(qw, s01), pk_add(dot01, dot01));  // dot+dot == 2*dot exactly
    d23 = pk_sub(pk_add(qw, s23), pk_add(dot23, dot23));
}

// x-sort bin (identical expression everywhere -> deterministic)
__device__ __forceinline__ int xbin(float x) {
    int b = (int)((x + 4.0f) * 32.0f);
    return b < 0 ? 0 : (b > 255 ? 255 : b);
}

// ---------------- sort-prep kernels ----------------

__global__ void zero_kernel(int* __restrict__ hist, int* __restrict__ tlo, int* __restrict__ thi) {
    int t = threadIdx.x;
    hist[t] = 0;
    if (t < 32) { tlo[t] = 255; thi[t] = 0; }
}

__global__ void scan_kernel(const int* __restrict__ hist, int* __restrict__ cut,
                            int* __restrict__ tlo, int* __restrict__ thi) {
    __shared__ int tmp[256];
    int t = threadIdx.x;
    int v = hist[t];
    tmp[t] = v;
    __syncthreads();
    for (int off = 1; off < 256; off <<= 1) {
        int add = (t >= off) ? tmp[t - off] : 0;
        __syncthreads();
        tmp[t] += add;
        __syncthreads();
    }
    int end = tmp[t], start = end - v;
    cut[t] = start;                       // exclusive prefix
    if (v > 0) {                          // conservative per-tile bin range
        int ta = start >> 8, tb = (end - 1) >> 8;
        for (int x = ta; x <= tb; ++x) {
            atomicMin(&tlo[x], t);
            atomicMax(&thi[x], t);
        }
    }
}

// sorted tiles: per 256-slot tile: [x(256)|y(256)|z(256)|sq(256)|idx(256)] (5120B)
__global__ void assign_kernel(const float* __restrict__ xyz, int* __restrict__ cut,
                              float* __restrict__ stile) {
    int i = blockIdx.x * 256 + threadIdx.x;
    float x = xyz[i*3+0], y = xyz[i*3+1], z = xyz[i*3+2];
    int pos = atomicAdd(&cut[xbin(x)], 1);
    float sq = __fadd_rn(__fadd_rn(__fmul_rn(x,x), __fmul_rn(y,y)), __fmul_rn(z,z));
    float* tp = stile + (pos >> 8) * 1280 + (pos & 255);
    tp[0] = x; tp[256] = y; tp[512] = z; tp[768] = sq;
    reinterpret_cast<int*>(tp)[1024] = i;
}

// ---------------- fused prep: Xb rows + Wpt + x-histogram ----------------

__global__ void prep_all(const float* __restrict__ feat, const float* __restrict__ xyz,
                         const float* __restrict__ W1,
                         __hip_bfloat16* __restrict__ Xb, __hip_bfloat16* __restrict__ Wpt,
                         int* __restrict__ hist) {
    int b = blockIdx.x;
    int t = threadIdx.x;
    if (b < N) {
        if (t < 96) {  // vectorized feat copy: 96 x float4 -> 4 x bf16
            float4 f = reinterpret_cast<const float4*>(feat + (size_t)b*TD)[t];
            __hip_bfloat16 h[4] = {__float2bfloat16(f.x), __float2bfloat16(f.y),
                                   __float2bfloat16(f.z), __float2bfloat16(f.w)};
            *reinterpret_cast<ulonglong1*>(Xb + b*KP + t*4) = *reinterpret_cast<ulonglong1*>(h);
        } else if (t == 96) {  // xyz tail + zero pad
            for (int d = TD; d < KP; ++d) {
                float v = (d < DX) ? xyz[b*3 + (d - TD)] : 0.f;
                Xb[b*KP + d] = __float2bfloat16(v);
            }
        } else if (t == 97) {  // histogram
            atomicAdd(&hist[xbin(xyz[b*3])], 1);
        }
    } else {
        int f = b - N;  // 0..767
        for (int k = t; k < KP; k += 256) {
            float v = 0.f;
            if (k < DX) {
                if (f < TD) v = W1[k*TD + f] - W1[(DX+k)*TD + f];
                else        v = W1[(DX+k)*TD + (f - TD)];
            }
            Wpt[f*KP + k] = __float2bfloat16(v);
        }
    }
}

// ---------------- knn helpers ----------------

__device__ __forceinline__ float dpp_shr1_f(float v) {
    return __uint_as_float((unsigned)__builtin_amdgcn_update_dpp(
        (int)__float_as_uint(v), (int)__float_as_uint(v), 0x111, 0xF, 0xF, false));
}
__device__ __forceinline__ int dpp_shr1_i(int v) {
    return __builtin_amdgcn_update_dpp(v, v, 0x111, 0xF, 0xF, false);
}
__device__ __forceinline__ float rdlane_f(float v, int src) {
    return __uint_as_float(__builtin_amdgcn_readlane(__float_as_uint(v), src));
}

// Sorted-by-lane top-16 insert with per-candidate orig-idx payload.
__device__ __forceinline__ void insert16p(float dv, int cjv, float Tq,
                                          float& ld, int& li, float& Tl, int lane) {
    unsigned long long m = __ballot((dv <= Tq) && (dv < Tl));
    while (m) {
        int src = (int)__ffsll(m) - 1;
        float cd = rdlane_f(dv, src);
        int   cj = __builtin_amdgcn_readlane(cjv, src);
        bool lt = (ld < cd) || (ld == cd && li < cj);
        int pos = (int)__popcll(__ballot(lt) & 0xFFFFull);
        float ud = dpp_shr1_f(ld);
        int   ui = dpp_shr1_i(li);
        ld = (lane == pos) ? cd : ((lane > pos) ? ud : ld);
        li = (lane == pos) ? cj : ((lane > pos) ? ui : li);
        Tl = rdlane_f(ld, 15);
        m &= ~(1ull << src);
        m &= __ballot(dv < Tl);
    }
}

// ---------------- knn: wave-pair per 4 sorted queries; 5-tile pass-1; pruned pass-2 ----------------

__global__ void __launch_bounds__(256) knn_kernel(const float* __restrict__ stile,
                                                  const int* __restrict__ tlo,
                                                  const int* __restrict__ thi,
                                                  int* __restrict__ knn) {
    __shared__ float sdl[2][2][4][16];
    __shared__ int   sjl[2][2][4][16];
    const int lane = threadIdx.x & 63;
    const int wv   = threadIdx.x >> 6;
    const int g    = wv >> 1;                    // query group in block (0,1)
    const int p    = wv & 1;                     // parity half (0,1)
    const int s0   = (blockIdx.x * 2 + g) * 4;   // 4 consecutive sorted slots
    const int tq   = s0 >> 8;
    const int sl   = (s0 & 255) >> 2;            // self lane; query q -> slot q

    const float* qp = stile + tq*1280 + (s0 & 255);
    float4 QX = *(const float4*)(qp);
    float4 QY = *(const float4*)(qp + 256);
    float4 QZ = *(const float4*)(qp + 512);
    float4 QW = *(const float4*)(qp + 768);
    int4   QI = *(const int4*)(qp + 1024);
    float qxa[4] = {QX.x, QX.y, QX.z, QX.w};
    int   qia[4] = {QI.x, QI.y, QI.z, QI.w};
    f32x2 qx2[4], qy2[4], qz2[4], qw2[4];
    {
        float qya[4] = {QY.x,QY.y,QY.z,QY.w};
        float qza[4] = {QZ.x,QZ.y,QZ.z,QZ.w}, qwa[4] = {QW.x,QW.y,QW.z,QW.w};
        #pragma unroll
        for (int q = 0; q < 4; ++q) {
            qx2[q] = (f32x2){qxa[q], qxa[q]};
            qy2[q] = (f32x2){qya[q], qya[q]};
            qz2[q] = (f32x2){qza[q], qza[q]};
            qw2[q] = (f32x2){qwa[q], qwa[q]};
        }
    }

    const float* lbase = stile + lane*4;
    const bool is_self_lane = (lane == sl);

    // ---- pass 1: lane minima over 5-tile x-window (disjoint candidate sets) ----
    float mn[4] = {INFF, INFF, INFF, INFF};
    int lo = tq - 2; if (lo < 0) lo = 0; if (lo > 27) lo = 27;
    for (int tt = 0; tt < 5; ++tt) {
        const int t = lo + tt;
        const float* tp = lbase + t*1280;
        float4 X = *(const float4*)(tp);
        float4 Y = *(const float4*)(tp + 256);
        float4 Z = *(const float4*)(tp + 512);
        float4 S = *(const float4*)(tp + 768);
        f32x2 x01 = {X.x,X.y}, x23 = {X.z,X.w};
        f32x2 y01 = {Y.x,Y.y}, y23 = {Y.z,Y.w};
        f32x2 z01 = {Z.x,Z.y}, z23 = {Z.z,Z.w};
        f32x2 s01 = {S.x,S.y}, s23 = {S.z,S.w};
        const bool selft = (t == tq) && is_self_lane;
        #pragma unroll
        for (int q = 0; q < 4; ++q) {
            f32x2 d01, d23;
            dist4(qx2[q], qy2[q], qz2[q], qw2[q],
                  x01, x23, y01, y23, z01, z23, s01, s23, d01, d23);
            if (selft) {
                if      (q == 0) d01[0] = INFF;
                else if (q == 1) d01[1] = INFF;
                else if (q == 2) d23[0] = INFF;
                else             d23[1] = INFF;
            }
            mn[q] = fminf(mn[q], fminf(fminf(d01[0], d01[1]), fminf(d23[0], d23[1])));
        }
    }

    // ---- T[q] = exact 16th smallest of the 64 lane minima (radix-select) ----
    unsigned ub[4];
    unsigned long long alive[4];
    int need[4];
    #pragma unroll
    for (int q = 0; q < 4; ++q) {
        unsigned x = __float_as_uint(mn[q]);
        ub[q] = ((int)x < 0) ? ~x : (x | 0x80000000u);
        alive[q] = ~0ull;
        need[q] = KNN;
    }
    for (int b = 31; b >= 0; --b) {
        #pragma unroll
        for (int q = 0; q < 4; ++q) {
            unsigned long long ones  = __ballot(((ub[q] >> b) & 1u) != 0u);
            unsigned long long zeros = alive[q] & ~ones;
            int cz = (int)__popcll(zeros);
            bool tz = (cz >= need[q]);
            alive[q] = tz ? zeros : (alive[q] & ones);
            need[q]  = tz ? need[q] : (need[q] - cz);
        }
    }
    float T[4];
    #pragma unroll
    for (int q = 0; q < 4; ++q)
        T[q] = fmaxf(rdlane_f(mn[q], (int)__ffsll(alive[q]) - 1), 0.f);  // clamp: skip-bound safety

    // ---- pass 2: expanding ring over this wave's parity tiles, x-bound pruning ----
    float ld[4] = {INFF, INFF, INFF, INFF};
    int   li[4] = {-1, -1, -1, -1};
    float Tl[4] = {INFF, INFF, INFF, INFF};

    for (int r = 0; r < 32; ++r) {
        const int t = tq + ((r & 1) ? -((r + 1) >> 1) : (r >> 1));
        if (t < 0 || t > 31) continue;
        if ((t & 1) != p) continue;
        // conservative tile x-range from bin edges (exact dyadics; edge bins open)
        const int bl = tlo[t], bh = thi[t];
        const float xlo = (bl == 0)   ? -1e30f : (bl * 0.03125f - 4.0f);
        const float xhi = (bh == 255) ?  1e30f : ((bh + 1) * 0.03125f - 4.0f);
        bool anyq = false;
        #pragma unroll
        for (int q = 0; q < 4; ++q) {
            float gap = fmaxf(0.f, fmaxf(xlo - qxa[q], qxa[q] - xhi));
            anyq = anyq || (gap * gap <= T[q] + 1e-3f);   // margin >> all fp32 rounding
        }
        if (!anyq) continue;

        const float* tp = lbase + t*1280;
        float4 X = *(const float4*)(tp);
        float4 Y = *(const float4*)(tp + 256);
        float4 Z = *(const float4*)(tp + 512);
        float4 S = *(const float4*)(tp + 768);
        int4   I = *(const int4*)(tp + 1024);
        f32x2 x01 = {X.x,X.y}, x23 = {X.z,X.w};
        f32x2 y01 = {Y.x,Y.y}, y23 = {Y.z,Y.w};
        f32x2 z01 = {Z.x,Z.y}, z23 = {Z.z,Z.w};
        f32x2 s01 = {S.x,S.y}, s23 = {S.z,S.w};
        const bool selft = (t == tq) && is_self_lane;
        #pragma unroll
        for (int q = 0; q < 4; ++q) {
            f32x2 d01, d23;
            dist4(qx2[q], qy2[q], qz2[q], qw2[q],
                  x01, x23, y01, y23, z01, z23, s01, s23, d01, d23);
            if (selft) {
                if      (q == 0) d01[0] = INFF;
                else if (q == 1) d01[1] = INFF;
                else if (q == 2) d23[0] = INFF;
                else             d23[1] = INFF;
            }
            float tmin = fminf(fminf(d01[0], d01[1]), fminf(d23[0], d23[1]));
            if (__ballot(tmin <= T[q])) {
                insert16p(d01[0], I.x, T[q], ld[q], li[q], Tl[q], lane);
                insert16p(d01[1], I.y, T[q], ld[q], li[q], Tl[q], lane);
                insert16p(d23[0], I.z, T[q], ld[q], li[q], Tl[q], lane);
                insert16p(d23[1], I.w, T[q], ld[q], li[q], Tl[q], lane);
            }
        }
    }

    // ---- merge the two parity halves' sorted-16 lists (bitonic half-cleaner) ----
    if (lane < KNN) {
        #pragma unroll
        for (int q = 0; q < 4; ++q) { sdl[g][p][q][lane] = ld[q]; sjl[g][p][q][lane] = li[q]; }
    }
    __syncthreads();
    if (p == 0 && lane < KNN) {
        #pragma unroll
        for (int q = 0; q < 4; ++q) {
            float ad = sdl[g][0][q][lane];      int aj = sjl[g][0][q][lane];
            float bd = sdl[g][1][q][15 - lane]; int bj = sjl[g][1][q][15 - lane];
            bool alt = (ad < bd) || (ad == bd && aj < bj);
            knn[qia[q]*KNN + lane] = alt ? aj : bj;
        }
    }
}

// ---------------- GEMM: Ub/Vb[N][384] = Xb @ Wpt^T (+ b1 on U), bf16 out ----------------
// 1 wave per block, 64 rows x 64 cols; C/D: col = lane&15, row = (lane>>4)*4 + q

__global__ void __launch_bounds__(64) gemm_kernel(const __hip_bfloat16* __restrict__ Xb,
                                                  const __hip_bfloat16* __restrict__ Wpt,
                                                  const float* __restrict__ b1,
                                                  __hip_bfloat16* __restrict__ Ub,
                                                  __hip_bfloat16* __restrict__ Vb) {
    const int lane = threadIdx.x;
    const int i0   = blockIdx.x * 64;
    const int f0   = blockIdx.y * 64;
    const int lm   = lane & 15;
    const int lk   = (lane >> 4) * 8;

    f32x4 acc[4][4];
    #pragma unroll
    for (int r = 0; r < 4; ++r)
        #pragma unroll
        for (int c = 0; c < 4; ++c)
            acc[r][c] = (f32x4){0.f, 0.f, 0.f, 0.f};

    const __hip_bfloat16* xbase = Xb  + (size_t)(i0 + lm) * KP + lk;
    const __hip_bfloat16* wbase = Wpt + (size_t)(f0 + lm) * KP + lk;

    #pragma unroll
    for (int kk = 0; kk < 13; ++kk) {
        short8 a[4], b[4];
        #pragma unroll
        for (int r = 0; r < 4; ++r)
            a[r] = *reinterpret_cast<const short8*>(xbase + (size_t)r*16*KP + kk*32);
        #pragma unroll
        for (int c = 0; c < 4; ++c)
            b[c] = *reinterpret_cast<const short8*>(wbase + (size_t)c*16*KP + kk*32);
        #pragma unroll
        for (int r = 0; r < 4; ++r)
            #pragma unroll
            for (int c = 0; c < 4; ++c)
                acc[r][c] = __builtin_amdgcn_mfma_f32_16x16x32_bf16(a[r], b[c], acc[r][c], 0, 0, 0);
    }

    const bool isU = (f0 < TD);
    __hip_bfloat16* outb = isU ? (Ub + f0) : (Vb + (f0 - TD));
    float bias[4] = {0.f, 0.f, 0.f, 0.f};
    if (isU) {
        #pragma unroll
        for (int c = 0; c < 4; ++c) bias[c] = b1[f0 + c*16 + lm];
    }
    const int crow = (lane >> 4) * 4;
    #pragma unroll
    for (int r = 0; r < 4; ++r)
        #pragma unroll
        for (int c = 0; c < 4; ++c)
            #pragma unroll
            for (int q = 0; q < 4; ++q)
                outb[(size_t)(i0 + r*16 + crow + q) * TD + c*16 + lm] =
                    __float2bfloat16(acc[r][c][q] + bias[c]);
}

// ---------------- final: dim-parallel (lane owns 6 dims), coalesced row reads ----------------
// Validated round 11: depth-2 batch pipeline, buffered partials, pipelined DPP reduce.

__device__ __forceinline__ float bflo(unsigned w) { return __uint_as_float(w << 16); }
__device__ __forceinline__ float bfhi(unsigned w) { return __uint_as_float(w & 0xFFFF0000u); }

template<int CTRL>
__device__ __forceinline__ float dppf(float v) {
    return __uint_as_float((unsigned)__builtin_amdgcn_update_dpp(
        0, (int)__float_as_uint(v), CTRL, 0xF, 0xF, true));
}

__global__ void __launch_bounds__(256) final_kernel(const __hip_bfloat16* __restrict__ Ub,
                                                    const __hip_bfloat16* __restrict__ Vb,
                                                    const int* __restrict__ knn,
                                                    const float* __restrict__ xyz,
                                                    const float* __restrict__ W2,
                                                    const float* __restrict__ b2,
                                                    float* __restrict__ out) {
    const int lane = threadIdx.x & 63;
    const int wv   = threadIdx.x >> 6;
    const int i    = blockIdx.x * 4 + wv;
    const int d0   = lane * 6;

    int jreg = knn[i*KNN + (lane & 15)];

    float u[6], w2l[6][3];
    {
        const unsigned* rowU = reinterpret_cast<const unsigned*>(Ub + (size_t)i * TD) + lane*3;
        unsigned a0 = rowU[0], a1 = rowU[1], a2 = rowU[2];
        u[0] = bflo(a0); u[1] = bfhi(a0);
        u[2] = bflo(a1); u[3] = bfhi(a1);
        u[4] = bflo(a2); u[5] = bfhi(a2);
    }
    #pragma unroll
    for (int t = 0; t < 6; ++t)
        #pragma unroll
        for (int c = 0; c < 3; ++c) w2l[t][c] = W2[(d0 + t)*3 + c];

    const unsigned* vbase = reinterpret_cast<const unsigned*>(Vb);
    const int voff = lane * 3;

    float pk0[16], pk1[16], pk2[16];
    unsigned va[2][4][3];

    #pragma unroll
    for (int t = 0; t < 4; ++t) {
        int j = __builtin_amdgcn_readlane(jreg, t);
        const unsigned* rv = vbase + (size_t)j * 192 + voff;
        va[0][t][0] = rv[0]; va[0][t][1] = rv[1]; va[0][t][2] = rv[2];
    }
    __builtin_amdgcn_sched_barrier(0);

    #pragma unroll
    for (int b = 0; b < 4; ++b) {
        if (b < 3) {
            #pragma unroll
            for (int t = 0; t < 4; ++t) {
                int j = __builtin_amdgcn_readlane(jreg, (b+1)*4 + t);
                const unsigned* rv = vbase + (size_t)j * 192 + voff;
                va[(b+1)&1][t][0] = rv[0];
                va[(b+1)&1][t][1] = rv[1];
                va[(b+1)&1][t][2] = rv[2];
            }
            __builtin_amdgcn_sched_barrier(0);
        }
        #pragma unroll
        for (int t = 0; t < 4; ++t) {
            const int kk = b*4 + t;
            unsigned a0 = va[b&1][t][0], a1 = va[b&1][t][1], a2 = va[b&1][t][2];
            float v0 = bflo(a0), v1 = bfhi(a0);
            float v2 = bflo(a1), v3 = bfhi(a1);
            float v4 = bflo(a2), v5 = bfhi(a2);
            float h0 = fmaxf(u[0] + v0, 0.f), h1 = fmaxf(u[1] + v1, 0.f);
            float h2 = fmaxf(u[2] + v2, 0.f), h3 = fmaxf(u[3] + v3, 0.f);
            float h4 = fmaxf(u[4] + v4, 0.f), h5 = fmaxf(u[5] + v5, 0.f);
            float s0 = 0.f, s1 = 0.f, s2 = 0.f;
            s0 = fmaf(h0, w2l[0][0], s0); s1 = fmaf(h0, w2l[0][1], s1); s2 = fmaf(h0, w2l[0][2], s2);
            s0 = fmaf(h1, w2l[1][0], s0); s1 = fmaf(h1, w2l[1][1], s1); s2 = fmaf(h1, w2l[1][2], s2);
            s0 = fmaf(h2, w2l[2][0], s0); s1 = fmaf(h2, w2l[2][1], s1); s2 = fmaf(h2, w2l[2][2], s2);
            s0 = fmaf(h3, w2l[3][0], s0); s1 = fmaf(h3, w2l[3][1], s1); s2 = fmaf(h3, w2l[3][2], s2);
            s0 = fmaf(h4, w2l[4][0], s0); s1 = fmaf(h4, w2l[4][1], s1); s2 = fmaf(h4, w2l[4][2], s2);
            s0 = fmaf(h5, w2l[5][0], s0); s1 = fmaf(h5, w2l[5][1], s1); s2 = fmaf(h5, w2l[5][2], s2);
            pk0[kk] = s0; pk1[kk] = s1; pk2[kk] = s2;
        }
    }

    #pragma unroll
    for (int kk = 0; kk < 16; ++kk) {
        float r0 = pk0[kk], r1 = pk1[kk], r2 = pk2[kk];
        r0 += dppf<0x121>(r0); r1 += dppf<0x121>(r1); r2 += dppf<0x121>(r2);
        r0 += dppf<0x122>(r0); r1 += dppf<0x122>(r1); r2 += dppf<0x122>(r2);
        r0 += dppf<0x124>(r0); r1 += dppf<0x124>(r1); r2 += dppf<0x124>(r2);
        r0 += dppf<0x128>(r0); r1 += dppf<0x128>(r1); r2 += dppf<0x128>(r2);
        r0 += __shfl_xor(r0, 16); r1 += __shfl_xor(r1, 16); r2 += __shfl_xor(r2, 16);
        r0 += __shfl_xor(r0, 32); r1 += __shfl_xor(r1, 32); r2 += __shfl_xor(r2, 32);
        pk0[kk] = r0; pk1[kk] = r1; pk2[kk] = r2;
    }
    float mx0 = pk0[0], mx1 = pk1[0], mx2 = pk2[0];
    #pragma unroll
    for (int kk = 1; kk < 16; ++kk) {
        mx0 = fmaxf(mx0, pk0[kk]);
        mx1 = fmaxf(mx1, pk1[kk]);
        mx2 = fmaxf(mx2, pk2[kk]);
    }

    if (lane == 0) {
        out[i*3+0] = xyz[i*3+0] + mx0 + b2[0];
        out[i*3+1] = xyz[i*3+1] + mx1 + b2[1];
        out[i*3+2] = xyz[i*3+2] + mx2 + b2[2];
    }
}

// ---------------- launch ----------------

extern "C" void kernel_launch(void* const* d_in, const int* in_sizes, int n_in,
                              void* d_out, int out_size, void* d_ws, size_t ws_size,
                              hipStream_t stream) {
    const float* xyz  = (const float*)d_in[0];
    const float* feat = (const float*)d_in[1];
    const float* W1   = (const float*)d_in[2];
    const float* b1   = (const float*)d_in[3];
    const float* W2   = (const float*)d_in[4];
    const float* b2   = (const float*)d_in[5];
    float* out = (float*)d_out;

    char* ws = (char*)d_ws;
    int*            knn   = (int*)(ws + 0);                   //   524288 B
    float*          stile = (float*)(ws + 524288);            //   163840 B
    __hip_bfloat16* Xb    = (__hip_bfloat16*)(ws + 688128);   //  6815744 B
    __hip_bfloat16* Wpt   = (__hip_bfloat16*)(ws + 7503872);  //   638976 B
    __hip_bfloat16* Ub    = (__hip_bfloat16*)(ws + 8142848);  //  6291456 B
    __hip_bfloat16* Vb    = (__hip_bfloat16*)(ws + 14434304); //  6291456 B
    int*            hist  = (int*)(ws + 20725760);            //     1024 B
    int*            cut   = (int*)(ws + 20726784);            //     1024 B
    int*            tlo   = (int*)(ws + 20727808);            //      128 B
    int*            thi   = (int*)(ws + 20727936);            //      128 B -> end 20728064

    zero_kernel  <<<dim3(1),           dim3(256), 0, stream>>>(hist, tlo, thi);
    prep_all     <<<dim3(N + NF),      dim3(256), 0, stream>>>(feat, xyz, W1, Xb, Wpt, hist);
    scan_kernel  <<<dim3(1),           dim3(256), 0, stream>>>(hist, cut, tlo, thi);
    assign_kernel<<<dim3(N/256),       dim3(256), 0, stream>>>(xyz, cut, stile);
    knn_kernel   <<<dim3(N/8),         dim3(256), 0, stream>>>(stile, tlo, thi, knn);
    gemm_kernel  <<<dim3(N/64, NF/64), dim3(64),  0, stream>>>(Xb, Wpt, b1, Ub, Vb);
    final_kernel <<<dim3(N/4),         dim3(256), 0, stream>>>(Ub, Vb, knn, xyz, W2, b2, out);
}

// Round 13
// 117.815 us; speedup vs baseline: 1.0376x; 1.0376x over previous
//
#include <hip/hip_runtime.h>
#include <hip/hip_bf16.h>

// GNNRefiner: out = xyz + max_k( relu([x_i, x_j-x_i]·W1 + b1)·W2 + b2 )
// Factorization: e·W1 = x_i·(A-B) + x_j·B  with A=W1[0:387], B=W1[387:774].
// Pipeline: sort(1 block: hist+scan+tile-bounds+scatter) -> prep -> knn (parity-split
//           pass-1 T, register-mask pruned pass-2) -> bf16 MFMA GEMM -> final (r11).
// KNN pruning: tile skipped iff gap^2 > T + 1e-3 (gap = x-gap to tile bin range);
// T = 16th-smallest of 64 disjoint-set lane minima (provable D16 upper bound).

#define N 8192
#define TD 384      // TOKEN_DIM
#define KNN 16
#define DX 387      // TD + 3
#define KP 416      // DX padded to multiple of 32
#define NF 768      // 2*TD output cols of fused GEMM
#define INFF __builtin_inff()

typedef __attribute__((ext_vector_type(8))) short short8;
typedef __attribute__((ext_vector_type(4))) float f32x4;
typedef __attribute__((ext_vector_type(2))) float f32x2;

// ---------------- packed fp32 helpers (bit-identical to scalar ops, 2 cands/instr) ----------------

__device__ __forceinline__ f32x2 pk_mul(f32x2 a, f32x2 b) {
    f32x2 r; asm("v_pk_mul_f32 %0, %1, %2" : "=v"(r) : "v"(a), "v"(b)); return r;
}
__device__ __forceinline__ f32x2 pk_add(f32x2 a, f32x2 b) {
    f32x2 r; asm("v_pk_add_f32 %0, %1, %2" : "=v"(r) : "v"(a), "v"(b)); return r;
}
__device__ __forceinline__ f32x2 pk_sub(f32x2 a, f32x2 b) {  // a - b, same rounding as fsub
    f32x2 r; asm("v_pk_add_f32 %0, %1, %2 neg_lo:[0,1] neg_hi:[0,1]" : "=v"(r) : "v"(a), "v"(b)); return r;
}
__device__ __forceinline__ f32x2 pk_fma(f32x2 a, f32x2 b, f32x2 c) {
    f32x2 r; asm("v_pk_fma_f32 %0, %1, %2, %3" : "=v"(r) : "v"(a), "v"(b), "v"(c)); return r;
}

// d2 = (qw + sq_j) - 2*dot, dot = fma(qz,z, fma(qy,y, mul(qx,x)))  [bit-identical to ref]
__device__ __forceinline__ void dist4(f32x2 qx, f32x2 qy, f32x2 qz, f32x2 qw,
                                      f32x2 x01, f32x2 x23, f32x2 y01, f32x2 y23,
                                      f32x2 z01, f32x2 z23, f32x2 s01, f32x2 s23,
                                      f32x2& d01, f32x2& d23) {
    f32x2 dot01 = pk_fma(qz, z01, pk_fma(qy, y01, pk_mul(qx, x01)));
    f32x2 dot23 = pk_fma(qz, z23, pk_fma(qy, y23, pk_mul(qx, x23)));
    d01 = pk_sub(pk_add(qw, s01), pk_add(dot01, dot01));  // dot+dot == 2*dot exactly
    d23 = pk_sub(pk_add(qw, s23), pk_add(dot23, dot23));
}

// x-sort bin (identical expression everywhere -> deterministic)
__device__ __forceinline__ int xbin(float x) {
    int b = (int)((x + 4.0f) * 32.0f);
    return b < 0 ? 0 : (b > 255 ? 255 : b);
}

// ---------------- sort: ONE single-block kernel (hist + scan + bounds + scatter) ----------------
// sorted tiles: per 256-slot tile: [x(256)|y(256)|z(256)|sq(256)|idx(256)] (5120B)

__global__ void __launch_bounds__(1024) sort_kernel(const float* __restrict__ xyz,
                                                    float* __restrict__ stile,
                                                    int* __restrict__ tlo,
                                                    int* __restrict__ thi) {
    __shared__ int hcnt[256];
    __shared__ int tmp[256];
    __shared__ int stlo[32], sthi[32];
    const int t = threadIdx.x;

    if (t < 256) hcnt[t] = 0;
    if (t < 32)  { stlo[t] = 255; sthi[t] = 0; }
    __syncthreads();

    int   bins[8];
    float xs[8], ys[8], zs[8];
    #pragma unroll
    for (int r = 0; r < 8; ++r) {
        int i = t + r*1024;
        xs[r] = xyz[i*3+0]; ys[r] = xyz[i*3+1]; zs[r] = xyz[i*3+2];
        bins[r] = xbin(xs[r]);
        atomicAdd(&hcnt[bins[r]], 1);
    }
    __syncthreads();

    if (t < 256) tmp[t] = hcnt[t];
    __syncthreads();
    for (int off = 1; off < 256; off <<= 1) {
        int v = 0;
        if (t < 256 && t >= off) v = tmp[t - off];
        __syncthreads();
        if (t < 256) tmp[t] += v;
        __syncthreads();
    }
    // tmp = inclusive prefix; per-tile conservative bin range
    if (t < 256 && hcnt[t] > 0) {
        int end = tmp[t], start = end - hcnt[t];
        for (int x = start >> 8; x <= (end - 1) >> 8; ++x) {
            atomicMin(&stlo[x], t);
            atomicMax(&sthi[x], t);
        }
    }
    __syncthreads();
    if (t < 256) hcnt[t] = tmp[t] - hcnt[t];   // reuse as allocation cursor (exclusive prefix)
    __syncthreads();

    #pragma unroll
    for (int r = 0; r < 8; ++r) {
        int i = t + r*1024;
        int pos = atomicAdd(&hcnt[bins[r]], 1);
        float sq = __fadd_rn(__fadd_rn(__fmul_rn(xs[r],xs[r]), __fmul_rn(ys[r],ys[r])),
                             __fmul_rn(zs[r],zs[r]));
        float* tp = stile + (pos >> 8) * 1280 + (pos & 255);
        tp[0] = xs[r]; tp[256] = ys[r]; tp[512] = zs[r]; tp[768] = sq;
        reinterpret_cast<int*>(tp)[1024] = i;
    }
    if (t < 32) { tlo[t] = stlo[t]; thi[t] = sthi[t]; }
}

// ---------------- prep: Xb rows + Wpt ----------------

__global__ void prep_all(const float* __restrict__ feat, const float* __restrict__ xyz,
                         const float* __restrict__ W1,
                         __hip_bfloat16* __restrict__ Xb, __hip_bfloat16* __restrict__ Wpt) {
    int b = blockIdx.x;
    int t = threadIdx.x;
    if (b < N) {
        if (t < 96) {  // vectorized feat copy: 96 x float4 -> 4 x bf16
            float4 f = reinterpret_cast<const float4*>(feat + (size_t)b*TD)[t];
            __hip_bfloat16 h[4] = {__float2bfloat16(f.x), __float2bfloat16(f.y),
                                   __float2bfloat16(f.z), __float2bfloat16(f.w)};
            *reinterpret_cast<ulonglong1*>(Xb + b*KP + t*4) = *reinterpret_cast<ulonglong1*>(h);
        } else if (t == 96) {  // xyz tail + zero pad
            for (int d = TD; d < KP; ++d) {
                float v = (d < DX) ? xyz[b*3 + (d - TD)] : 0.f;
                Xb[b*KP + d] = __float2bfloat16(v);
            }
        }
    } else {
        int f = b - N;  // 0..767
        for (int k = t; k < KP; k += 256) {
            float v = 0.f;
            if (k < DX) {
                if (f < TD) v = W1[k*TD + f] - W1[(DX+k)*TD + f];
                else        v = W1[(DX+k)*TD + (f - TD)];
            }
            Wpt[f*KP + k] = __float2bfloat16(v);
        }
    }
}

// ---------------- knn helpers ----------------

__device__ __forceinline__ float dpp_shr1_f(float v) {
    return __uint_as_float((unsigned)__builtin_amdgcn_update_dpp(
        (int)__float_as_uint(v), (int)__float_as_uint(v), 0x111, 0xF, 0xF, false));
}
__device__ __forceinline__ int dpp_shr1_i(int v) {
    return __builtin_amdgcn_update_dpp(v, v, 0x111, 0xF, 0xF, false);
}
__device__ __forceinline__ float rdlane_f(float v, int src) {
    return __uint_as_float(__builtin_amdgcn_readlane(__float_as_uint(v), src));
}

// Sorted-by-lane top-16 insert with per-candidate orig-idx payload.
__device__ __forceinline__ void insert16p(float dv, int cjv, float Tq,
                                          float& ld, int& li, float& Tl, int lane) {
    unsigned long long m = __ballot((dv <= Tq) && (dv < Tl));
    while (m) {
        int src = (int)__ffsll(m) - 1;
        float cd = rdlane_f(dv, src);
        int   cj = __builtin_amdgcn_readlane(cjv, src);
        bool lt = (ld < cd) || (ld == cd && li < cj);
        int pos = (int)__popcll(__ballot(lt) & 0xFFFFull);
        float ud = dpp_shr1_f(ld);
        int   ui = dpp_shr1_i(li);
        ld = (lane == pos) ? cd : ((lane > pos) ? ud : ld);
        li = (lane == pos) ? cj : ((lane > pos) ? ui : li);
        Tl = rdlane_f(ld, 15);
        m &= ~(1ull << src);
        m &= __ballot(dv < Tl);
    }
}

// ---------------- knn: wave-pair per 4 sorted queries; parity-split both passes ----------------

__global__ void __launch_bounds__(256) knn_kernel(const float* __restrict__ stile,
                                                  const int* __restrict__ tlo,
                                                  const int* __restrict__ thi,
                                                  int* __restrict__ knn) {
    __shared__ float sdl[2][2][4][16];
    __shared__ int   sjl[2][2][4][16];
    const int lane = threadIdx.x & 63;
    const int wv   = threadIdx.x >> 6;
    const int g    = wv >> 1;                    // query group in block (0,1)
    const int p    = wv & 1;                     // parity half (0,1)
    const int s0   = (blockIdx.x * 2 + g) * 4;   // 4 consecutive sorted slots
    const int tq   = s0 >> 8;
    const int sl   = (s0 & 255) >> 2;            // self lane; query q -> slot q

    const float* qp = stile + tq*1280 + (s0 & 255);
    float4 QX = *(const float4*)(qp);
    float4 QY = *(const float4*)(qp + 256);
    float4 QZ = *(const float4*)(qp + 512);
    float4 QW = *(const float4*)(qp + 768);
    int4   QI = *(const int4*)(qp + 1024);
    float qxa[4] = {QX.x, QX.y, QX.z, QX.w};
    int   qia[4] = {QI.x, QI.y, QI.z, QI.w};
    f32x2 qx2[4], qy2[4], qz2[4], qw2[4];
    {
        float qya[4] = {QY.x,QY.y,QY.z,QY.w};
        float qza[4] = {QZ.x,QZ.y,QZ.z,QZ.w}, qwa[4] = {QW.x,QW.y,QW.z,QW.w};
        #pragma unroll
        for (int q = 0; q < 4; ++q) {
            qx2[q] = (f32x2){qxa[q], qxa[q]};
            qy2[q] = (f32x2){qya[q], qya[q]};
            qz2[q] = (f32x2){qza[q], qza[q]};
            qw2[q] = (f32x2){qwa[q], qwa[q]};
        }
    }

    const float* lbase = stile + lane*4;
    const bool is_self_lane = (lane == sl);

    // ---- pass 1: lane minima over this wave's parity tiles of the 5-tile window ----
    float mn[4] = {INFF, INFF, INFF, INFF};
    int lo = tq - 2; if (lo < 0) lo = 0; if (lo > 27) lo = 27;
    #pragma unroll
    for (int tt = 0; tt < 5; ++tt) {
        const int t = lo + tt;
        if ((t & 1) != p) continue;
        const float* tp = lbase + t*1280;
        float4 X = *(const float4*)(tp);
        float4 Y = *(const float4*)(tp + 256);
        float4 Z = *(const float4*)(tp + 512);
        float4 S = *(const float4*)(tp + 768);
        f32x2 x01 = {X.x,X.y}, x23 = {X.z,X.w};
        f32x2 y01 = {Y.x,Y.y}, y23 = {Y.z,Y.w};
        f32x2 z01 = {Z.x,Z.y}, z23 = {Z.z,Z.w};
        f32x2 s01 = {S.x,S.y}, s23 = {S.z,S.w};
        const bool selft = (t == tq) && is_self_lane;
        #pragma unroll
        for (int q = 0; q < 4; ++q) {
            f32x2 d01, d23;
            dist4(qx2[q], qy2[q], qz2[q], qw2[q],
                  x01, x23, y01, y23, z01, z23, s01, s23, d01, d23);
            if (selft) {
                if      (q == 0) d01[0] = INFF;
                else if (q == 1) d01[1] = INFF;
                else if (q == 2) d23[0] = INFF;
                else             d23[1] = INFF;
            }
            mn[q] = fminf(mn[q], fminf(fminf(d01[0], d01[1]), fminf(d23[0], d23[1])));
        }
    }

    // ---- T[q] = exact 16th smallest of the 64 lane minima (radix-select) ----
    unsigned ub[4];
    unsigned long long alive[4];
    int need[4];
    #pragma unroll
    for (int q = 0; q < 4; ++q) {
        unsigned x = __float_as_uint(mn[q]);
        ub[q] = ((int)x < 0) ? ~x : (x | 0x80000000u);
        alive[q] = ~0ull;
        need[q] = KNN;
    }
    for (int b = 31; b >= 0; --b) {
        #pragma unroll
        for (int q = 0; q < 4; ++q) {
            unsigned long long ones  = __ballot(((ub[q] >> b) & 1u) != 0u);
            unsigned long long zeros = alive[q] & ~ones;
            int cz = (int)__popcll(zeros);
            bool tz = (cz >= need[q]);
            alive[q] = tz ? zeros : (alive[q] & ones);
            need[q]  = tz ? need[q] : (need[q] - cz);
        }
    }
    float T[4];
    #pragma unroll
    for (int q = 0; q < 4; ++q)
        T[q] = fmaxf(rdlane_f(mn[q], (int)__ffsll(alive[q]) - 1), 0.f);  // clamp: skip-bound safety

    // ---- build visit mask in registers (one coalesced tlo/thi read, no per-tile loads) ----
    unsigned mask;
    {
        const int ti = lane & 31;
        const int bl = tlo[ti], bh = thi[ti];
        const float xlo = (bl == 0)   ? -1e30f : (bl * 0.03125f - 4.0f);
        const float xhi = (bh == 255) ?  1e30f : ((bh + 1) * 0.03125f - 4.0f);
        bool gate = false;
        #pragma unroll
        for (int q = 0; q < 4; ++q) {
            float gap = fmaxf(0.f, fmaxf(xlo - qxa[q], qxa[q] - xhi));
            gate = gate || (gap * gap <= T[q] + 1e-3f);   // margin >> all fp32 rounding
        }
        mask = (unsigned)__ballot(gate && (lane < 32));
        mask &= p ? 0xAAAAAAAAu : 0x55555555u;            // this wave's parity tiles
    }

    // ---- pass 2: iterate surviving tiles from the register mask ----
    float ld[4] = {INFF, INFF, INFF, INFF};
    int   li[4] = {-1, -1, -1, -1};
    float Tl[4] = {INFF, INFF, INFF, INFF};

    while (mask) {
        const int t = (int)__ffs(mask) - 1;
        mask &= mask - 1;
        const float* tp = lbase + t*1280;
        float4 X = *(const float4*)(tp);
        float4 Y = *(const float4*)(tp + 256);
        float4 Z = *(const float4*)(tp + 512);
        float4 S = *(const float4*)(tp + 768);
        int4   I = *(const int4*)(tp + 1024);
        f32x2 x01 = {X.x,X.y}, x23 = {X.z,X.w};
        f32x2 y01 = {Y.x,Y.y}, y23 = {Y.z,Y.w};
        f32x2 z01 = {Z.x,Z.y}, z23 = {Z.z,Z.w};
        f32x2 s01 = {S.x,S.y}, s23 = {S.z,S.w};
        const bool selft = (t == tq) && is_self_lane;
        #pragma unroll
        for (int q = 0; q < 4; ++q) {
            f32x2 d01, d23;
            dist4(qx2[q], qy2[q], qz2[q], qw2[q],
                  x01, x23, y01, y23, z01, z23, s01, s23, d01, d23);
            if (selft) {
                if      (q == 0) d01[0] = INFF;
                else if (q == 1) d01[1] = INFF;
                else if (q == 2) d23[0] = INFF;
                else             d23[1] = INFF;
            }
            float tmin = fminf(fminf(d01[0], d01[1]), fminf(d23[0], d23[1]));
            if (__ballot(tmin <= T[q])) {
                insert16p(d01[0], I.x, T[q], ld[q], li[q], Tl[q], lane);
                insert16p(d01[1], I.y, T[q], ld[q], li[q], Tl[q], lane);
                insert16p(d23[0], I.z, T[q], ld[q], li[q], Tl[q], lane);
                insert16p(d23[1], I.w, T[q], ld[q], li[q], Tl[q], lane);
            }
        }
    }

    // ---- merge the two parity halves' sorted-16 lists (bitonic half-cleaner) ----
    if (lane < KNN) {
        #pragma unroll
        for (int q = 0; q < 4; ++q) { sdl[g][p][q][lane] = ld[q]; sjl[g][p][q][lane] = li[q]; }
    }
    __syncthreads();
    if (p == 0 && lane < KNN) {
        #pragma unroll
        for (int q = 0; q < 4; ++q) {
            float ad = sdl[g][0][q][lane];      int aj = sjl[g][0][q][lane];
            float bd = sdl[g][1][q][15 - lane]; int bj = sjl[g][1][q][15 - lane];
            bool alt = (ad < bd) || (ad == bd && aj < bj);
            knn[qia[q]*KNN + lane] = alt ? aj : bj;
        }
    }
}

// ---------------- GEMM: Ub/Vb[N][384] = Xb @ Wpt^T (+ b1 on U), bf16 out ----------------
// 1 wave per block, 64 rows x 64 cols; C/D: col = lane&15, row = (lane>>4)*4 + q

__global__ void __launch_bounds__(64) gemm_kernel(const __hip_bfloat16* __restrict__ Xb,
                                                  const __hip_bfloat16* __restrict__ Wpt,
                                                  const float* __restrict__ b1,
                                                  __hip_bfloat16* __restrict__ Ub,
                                                  __hip_bfloat16* __restrict__ Vb) {
    const int lane = threadIdx.x;
    const int i0   = blockIdx.x * 64;
    const int f0   = blockIdx.y * 64;
    const int lm   = lane & 15;
    const int lk   = (lane >> 4) * 8;

    f32x4 acc[4][4];
    #pragma unroll
    for (int r = 0; r < 4; ++r)
        #pragma unroll
        for (int c = 0; c < 4; ++c)
            acc[r][c] = (f32x4){0.f, 0.f, 0.f, 0.f};

    const __hip_bfloat16* xbase = Xb  + (size_t)(i0 + lm) * KP + lk;
    const __hip_bfloat16* wbase = Wpt + (size_t)(f0 + lm) * KP + lk;

    #pragma unroll
    for (int kk = 0; kk < 13; ++kk) {
        short8 a[4], b[4];
        #pragma unroll
        for (int r = 0; r < 4; ++r)
            a[r] = *reinterpret_cast<const short8*>(xbase + (size_t)r*16*KP + kk*32);
        #pragma unroll
        for (int c = 0; c < 4; ++c)
            b[c] = *reinterpret_cast<const short8*>(wbase + (size_t)c*16*KP + kk*32);
        #pragma unroll
        for (int r = 0; r < 4; ++r)
            #pragma unroll
            for (int c = 0; c < 4; ++c)
                acc[r][c] = __builtin_amdgcn_mfma_f32_16x16x32_bf16(a[r], b[c], acc[r][c], 0, 0, 0);
    }

    const bool isU = (f0 < TD);
    __hip_bfloat16* outb = isU ? (Ub + f0) : (Vb + (f0 - TD));
    float bias[4] = {0.f, 0.f, 0.f, 0.f};
    if (isU) {
        #pragma unroll
        for (int c = 0; c < 4; ++c) bias[c] = b1[f0 + c*16 + lm];
    }
    const int crow = (lane >> 4) * 4;
    #pragma unroll
    for (int r = 0; r < 4; ++r)
        #pragma unroll
        for (int c = 0; c < 4; ++c)
            #pragma unroll
            for (int q = 0; q < 4; ++q)
                outb[(size_t)(i0 + r*16 + crow + q) * TD + c*16 + lm] =
                    __float2bfloat16(acc[r][c][q] + bias[c]);
}

// ---------------- final: dim-parallel (lane owns 6 dims), coalesced row reads ----------------
// Validated round 11: depth-2 batch pipeline, buffered partials, pipelined DPP reduce.

__device__ __forceinline__ float bflo(unsigned w) { return __uint_as_float(w << 16); }
__device__ __forceinline__ float bfhi(unsigned w) { return __uint_as_float(w & 0xFFFF0000u); }

template<int CTRL>
__device__ __forceinline__ float dppf(float v) {
    return __uint_as_float((unsigned)__builtin_amdgcn_update_dpp(
        0, (int)__float_as_uint(v), CTRL, 0xF, 0xF, true));
}

__global__ void __launch_bounds__(256) final_kernel(const __hip_bfloat16* __restrict__ Ub,
                                                    const __hip_bfloat16* __restrict__ Vb,
                                                    const int* __restrict__ knn,
                                                    const float* __restrict__ xyz,
                                                    const float* __restrict__ W2,
                                                    const float* __restrict__ b2,
                                                    float* __restrict__ out) {
    const int lane = threadIdx.x & 63;
    const int wv   = threadIdx.x >> 6;
    const int i    = blockIdx.x * 4 + wv;
    const int d0   = lane * 6;

    int jreg = knn[i*KNN + (lane & 15)];

    float u[6], w2l[6][3];
    {
        const unsigned* rowU = reinterpret_cast<const unsigned*>(Ub + (size_t)i * TD) + lane*3;
        unsigned a0 = rowU[0], a1 = rowU[1], a2 = rowU[2];
        u[0] = bflo(a0); u[1] = bfhi(a0);
        u[2] = bflo(a1); u[3] = bfhi(a1);
        u[4] = bflo(a2); u[5] = bfhi(a2);
    }
    #pragma unroll
    for (int t = 0; t < 6; ++t)
        #pragma unroll
        for (int c = 0; c < 3; ++c) w2l[t][c] = W2[(d0 + t)*3 + c];

    const unsigned* vbase = reinterpret_cast<const unsigned*>(Vb);
    const int voff = lane * 3;

    float pk0[16], pk1[16], pk2[16];
    unsigned va[2][4][3];

    #pragma unroll
    for (int t = 0; t < 4; ++t) {
        int j = __builtin_amdgcn_readlane(jreg, t);
        const unsigned* rv = vbase + (size_t)j * 192 + voff;
        va[0][t][0] = rv[0]; va[0][t][1] = rv[1]; va[0][t][2] = rv[2];
    }
    __builtin_amdgcn_sched_barrier(0);

    #pragma unroll
    for (int b = 0; b < 4; ++b) {
        if (b < 3) {
            #pragma unroll
            for (int t = 0; t < 4; ++t) {
                int j = __builtin_amdgcn_readlane(jreg, (b+1)*4 + t);
                const unsigned* rv = vbase + (size_t)j * 192 + voff;
                va[(b+1)&1][t][0] = rv[0];
                va[(b+1)&1][t][1] = rv[1];
                va[(b+1)&1][t][2] = rv[2];
            }
            __builtin_amdgcn_sched_barrier(0);
        }
        #pragma unroll
        for (int t = 0; t < 4; ++t) {
            const int kk = b*4 + t;
            unsigned a0 = va[b&1][t][0], a1 = va[b&1][t][1], a2 = va[b&1][t][2];
            float v0 = bflo(a0), v1 = bfhi(a0);
            float v2 = bflo(a1), v3 = bfhi(a1);
            float v4 = bflo(a2), v5 = bfhi(a2);
            float h0 = fmaxf(u[0] + v0, 0.f), h1 = fmaxf(u[1] + v1, 0.f);
            float h2 = fmaxf(u[2] + v2, 0.f), h3 = fmaxf(u[3] + v3, 0.f);
            float h4 = fmaxf(u[4] + v4, 0.f), h5 = fmaxf(u[5] + v5, 0.f);
            float s0 = 0.f, s1 = 0.f, s2 = 0.f;
            s0 = fmaf(h0, w2l[0][0], s0); s1 = fmaf(h0, w2l[0][1], s1); s2 = fmaf(h0, w2l[0][2], s2);
            s0 = fmaf(h1, w2l[1][0], s0); s1 = fmaf(h1, w2l[1][1], s1); s2 = fmaf(h1, w2l[1][2], s2);
            s0 = fmaf(h2, w2l[2][0], s0); s1 = fmaf(h2, w2l[2][1], s1); s2 = fmaf(h2, w2l[2][2], s2);
            s0 = fmaf(h3, w2l[3][0], s0); s1 = fmaf(h3, w2l[3][1], s1); s2 = fmaf(h3, w2l[3][2], s2);
            s0 = fmaf(h4, w2l[4][0], s0); s1 = fmaf(h4, w2l[4][1], s1); s2 = fmaf(h4, w2l[4][2], s2);
            s0 = fmaf(h5, w2l[5][0], s0); s1 = fmaf(h5, w2l[5][1], s1); s2 = fmaf(h5, w2l[5][2], s2);
            pk0[kk] = s0; pk1[kk] = s1; pk2[kk] = s2;
        }
    }

    #pragma unroll
    for (int kk = 0; kk < 16; ++kk) {
        float r0 = pk0[kk], r1 = pk1[kk], r2 = pk2[kk];
        r0 += dppf<0x121>(r0); r1 += dppf<0x121>(r1); r2 += dppf<0x121>(r2);
        r0 += dppf<0x122>(r0); r1 += dppf<0x122>(r1); r2 += dppf<0x122>(r2);
        r0 += dppf<0x124>(r0); r1 += dppf<0x124>(r1); r2 += dppf<0x124>(r2);
        r0 += dppf<0x128>(r0); r1 += dppf<0x128>(r1); r2 += dppf<0x128>(r2);
        r0 += __shfl_xor(r0, 16); r1 += __shfl_xor(r1, 16); r2 += __shfl_xor(r2, 16);
        r0 += __shfl_xor(r0, 32); r1 += __shfl_xor(r1, 32); r2 += __shfl_xor(r2, 32);
        pk0[kk] = r0; pk1[kk] = r1; pk2[kk] = r2;
    }
    float mx0 = pk0[0], mx1 = pk1[0], mx2 = pk2[0];
    #pragma unroll
    for (int kk = 1; kk < 16; ++kk) {
        mx0 = fmaxf(mx0, pk0[kk]);
        mx1 = fmaxf(mx1, pk1[kk]);
        mx2 = fmaxf(mx2, pk2[kk]);
    }

    if (lane == 0) {
        out[i*3+0] = xyz[i*3+0] + mx0 + b2[0];
        out[i*3+1] = xyz[i*3+1] + mx1 + b2[1];
        out[i*3+2] = xyz[i*3+2] + mx2 + b2[2];
    }
}

// ---------------- launch ----------------

extern "C" void kernel_launch(void* const* d_in, const int* in_sizes, int n_in,
                              void* d_out, int out_size, void* d_ws, size_t ws_size,
                              hipStream_t stream) {
    const float* xyz  = (const float*)d_in[0];
    const float* feat = (const float*)d_in[1];
    const float* W1   = (const float*)d_in[2];
    const float* b1   = (const float*)d_in[3];
    const float* W2   = (const float*)d_in[4];
    const float* b2   = (const float*)d_in[5];
    float* out = (float*)d_out;

    char* ws = (char*)d_ws;
    int*            knn   = (int*)(ws + 0);                   //   524288 B
    float*          stile = (float*)(ws + 524288);            //   163840 B
    __hip_bfloat16* Xb    = (__hip_bfloat16*)(ws + 688128);   //  6815744 B
    __hip_bfloat16* Wpt   = (__hip_bfloat16*)(ws + 7503872);  //   638976 B
    __hip_bfloat16* Ub    = (__hip_bfloat16*)(ws + 8142848);  //  6291456 B
    __hip_bfloat16* Vb    = (__hip_bfloat16*)(ws + 14434304); //  6291456 B
    int*            tlo   = (int*)(ws + 20725760);            //      128 B
    int*            thi   = (int*)(ws + 20725888);            //      128 B -> end 20726016

    sort_kernel  <<<dim3(1),           dim3(1024), 0, stream>>>(xyz, stile, tlo, thi);
    prep_all     <<<dim3(N + NF),      dim3(256),  0, stream>>>(feat, xyz, W1, Xb, Wpt);
    knn_kernel   <<<dim3(N/8),         dim3(256),  0, stream>>>(stile, tlo, thi, knn);
    gemm_kernel  <<<dim3(N/64, NF/64), dim3(64),   0, stream>>>(Xb, Wpt, b1, Ub, Vb);
    final_kernel <<<dim3(N/4),         dim3(256),  0, stream>>>(Ub, Vb, knn, xyz, W2, b2, out);
}

// Round 14
// 110.200 us; speedup vs baseline: 1.1093x; 1.0691x over previous
//
#include <hip/hip_runtime.h>
#include <hip/hip_bf16.h>

// GNNRefiner: out = xyz + max_k( relu([x_i, x_j-x_i]·W1 + b1)·W2 + b2 )
// Factorization: e·W1 = x_i·(A-B) + x_j·B  with A=W1[0:387], B=W1[387:774].
// Pipeline: memset(hist/cut/thi=0, tlo=0x7F) -> prep(+hist) -> assign(32 blk, local
//           scan + scatter + bounds) -> knn (1 query/WAVE, 5-tile pass-1 T,
//           register-mask pruned pass-2, 8 waves/SIMD) -> MFMA GEMM -> final (r11).
// KNN pruning: tile skipped iff gap^2 > T + 1e-3 (gap = x-gap to tile bin range);
// T = 16th-smallest of 64 disjoint-set lane minima (provable D16 upper bound).

#define N 8192
#define TD 384      // TOKEN_DIM
#define KNN 16
#define DX 387      // TD + 3
#define KP 416      // DX padded to multiple of 32
#define NF 768      // 2*TD output cols of fused GEMM
#define INFF __builtin_inff()

typedef __attribute__((ext_vector_type(8))) short short8;
typedef __attribute__((ext_vector_type(4))) float f32x4;
typedef __attribute__((ext_vector_type(2))) float f32x2;

// ---------------- packed fp32 helpers (bit-identical to scalar ops, 2 cands/instr) ----------------

__device__ __forceinline__ f32x2 pk_mul(f32x2 a, f32x2 b) {
    f32x2 r; asm("v_pk_mul_f32 %0, %1, %2" : "=v"(r) : "v"(a), "v"(b)); return r;
}
__device__ __forceinline__ f32x2 pk_add(f32x2 a, f32x2 b) {
    f32x2 r; asm("v_pk_add_f32 %0, %1, %2" : "=v"(r) : "v"(a), "v"(b)); return r;
}
__device__ __forceinline__ f32x2 pk_sub(f32x2 a, f32x2 b) {  // a - b, same rounding as fsub
    f32x2 r; asm("v_pk_add_f32 %0, %1, %2 neg_lo:[0,1] neg_hi:[0,1]" : "=v"(r) : "v"(a), "v"(b)); return r;
}
__device__ __forceinline__ f32x2 pk_fma(f32x2 a, f32x2 b, f32x2 c) {
    f32x2 r; asm("v_pk_fma_f32 %0, %1, %2, %3" : "=v"(r) : "v"(a), "v"(b), "v"(c)); return r;
}

// d2 = (qw + sq_j) - 2*dot, dot = fma(qz,z, fma(qy,y, mul(qx,x)))  [bit-identical to ref]
__device__ __forceinline__ void dist4(f32x2 qx, f32x2 qy, f32x2 qz, f32x2 qw,
                                      f32x2 x01, f32x2 x23, f32x2 y01, f32x2 y23,
                                      f32x2 z01, f32x2 z23, f32x2 s01, f32x2 s23,
                                      f32x2& d01, f32x2& d23) {
    f32x2 dot01 = pk_fma(qz, z01, pk_fma(qy, y01, pk_mul(qx, x01)));
    f32x2 dot23 = pk_fma(qz, z23, pk_fma(qy, y23, pk_mul(qx, x23)));
    d01 = pk_sub(pk_add(qw, s01), pk_add(dot01, dot01));  // dot+dot == 2*dot exactly
    d23 = pk_sub(pk_add(qw, s23), pk_add(dot23, dot23));
}

// x-sort bin (identical expression everywhere -> deterministic)
__device__ __forceinline__ int xbin(float x) {
    int b = (int)((x + 4.0f) * 32.0f);
    return b < 0 ? 0 : (b > 255 ? 255 : b);
}

// ---------------- prep: Xb rows + Wpt + x-histogram (128-thread blocks) ----------------

__global__ void __launch_bounds__(128) prep_all(const float* __restrict__ feat,
                                                const float* __restrict__ xyz,
                                                const float* __restrict__ W1,
                                                __hip_bfloat16* __restrict__ Xb,
                                                __hip_bfloat16* __restrict__ Wpt,
                                                int* __restrict__ hist) {
    int b = blockIdx.x;
    int t = threadIdx.x;
    if (b < N) {
        if (t < 96) {  // vectorized feat copy: 96 x float4 -> 4 x bf16
            float4 f = reinterpret_cast<const float4*>(feat + (size_t)b*TD)[t];
            __hip_bfloat16 h[4] = {__float2bfloat16(f.x), __float2bfloat16(f.y),
                                   __float2bfloat16(f.z), __float2bfloat16(f.w)};
            *reinterpret_cast<ulonglong1*>(Xb + b*KP + t*4) = *reinterpret_cast<ulonglong1*>(h);
        } else if (t == 96) {  // xyz tail + zero pad
            for (int d = TD; d < KP; ++d) {
                float v = (d < DX) ? xyz[b*3 + (d - TD)] : 0.f;
                Xb[b*KP + d] = __float2bfloat16(v);
            }
        } else if (t == 97) {  // histogram
            atomicAdd(&hist[xbin(xyz[b*3])], 1);
        }
    } else {
        int f = b - N;  // 0..767
        for (int k = t; k < KP; k += 128) {
            float v = 0.f;
            if (k < DX) {
                if (f < TD) v = W1[k*TD + f] - W1[(DX+k)*TD + f];
                else        v = W1[(DX+k)*TD + (f - TD)];
            }
            Wpt[f*KP + k] = __float2bfloat16(v);
        }
    }
}

// ---------------- assign: 32 blocks; local scan of hist + scatter + tile bounds ----------------
// sorted tiles: per 256-slot tile: [x(256)|y(256)|z(256)|sq(256)|idx(256)] (5120B)
// Slot order within a bin is atomic-nondeterministic; output invariant (selection is
// exact top-16 by (d, orig idx); tile membership + bounds come from the deterministic scan).

__global__ void __launch_bounds__(256) assign_kernel(const float* __restrict__ xyz,
                                                     const int* __restrict__ hist,
                                                     int* __restrict__ cut,
                                                     int* __restrict__ tlo,
                                                     int* __restrict__ thi,
                                                     float* __restrict__ stile) {
    __shared__ int tmp[256];
    const int t = threadIdx.x;
    int v = hist[t];
    tmp[t] = v;
    __syncthreads();
    for (int off = 1; off < 256; off <<= 1) {
        int add = (t >= off) ? tmp[t - off] : 0;
        __syncthreads();
        tmp[t] += add;
        __syncthreads();
    }
    const int end = tmp[t], start = end - v;   // inclusive / exclusive prefix for bin t
    __shared__ int base[256];
    base[t] = start;
    __syncthreads();

    if (blockIdx.x == 0 && v > 0) {            // conservative per-tile bin range
        for (int x = start >> 8; x <= (end - 1) >> 8; ++x) {
            atomicMin(&tlo[x], t);
            atomicMax(&thi[x], t);
        }
    }

    const int i = blockIdx.x * 256 + t;
    float x = xyz[i*3+0], y = xyz[i*3+1], z = xyz[i*3+2];
    int bin = xbin(x);
    int pos = base[bin] + atomicAdd(&cut[bin], 1);
    float sq = __fadd_rn(__fadd_rn(__fmul_rn(x,x), __fmul_rn(y,y)), __fmul_rn(z,z));
    float* tp = stile + (pos >> 8) * 1280 + (pos & 255);
    tp[0] = x; tp[256] = y; tp[512] = z; tp[768] = sq;
    reinterpret_cast<int*>(tp)[1024] = i;
}

// ---------------- knn helpers ----------------

__device__ __forceinline__ float dpp_shr1_f(float v) {
    return __uint_as_float((unsigned)__builtin_amdgcn_update_dpp(
        (int)__float_as_uint(v), (int)__float_as_uint(v), 0x111, 0xF, 0xF, false));
}
__device__ __forceinline__ int dpp_shr1_i(int v) {
    return __builtin_amdgcn_update_dpp(v, v, 0x111, 0xF, 0xF, false);
}
__device__ __forceinline__ float rdlane_f(float v, int src) {
    return __uint_as_float(__builtin_amdgcn_readlane(__float_as_uint(v), src));
}

// Sorted-by-lane top-16 insert with per-candidate orig-idx payload.
__device__ __forceinline__ void insert16p(float dv, int cjv, float Tq,
                                          float& ld, int& li, float& Tl, int lane) {
    unsigned long long m = __ballot((dv <= Tq) && (dv < Tl));
    while (m) {
        int src = (int)__ffsll(m) - 1;
        float cd = rdlane_f(dv, src);
        int   cj = __builtin_amdgcn_readlane(cjv, src);
        bool lt = (ld < cd) || (ld == cd && li < cj);
        int pos = (int)__popcll(__ballot(lt) & 0xFFFFull);
        float ud = dpp_shr1_f(ld);
        int   ui = dpp_shr1_i(li);
        ld = (lane == pos) ? cd : ((lane > pos) ? ud : ld);
        li = (lane == pos) ? cj : ((lane > pos) ? ui : li);
        Tl = rdlane_f(ld, 15);
        m &= ~(1ull << src);
        m &= __ballot(dv < Tl);
    }
}

// ---------------- knn: ONE query per wave; full 5-tile pass-1; mask-pruned pass-2 ----------------

__global__ void __launch_bounds__(256, 8) knn_kernel(const float* __restrict__ stile,
                                                     const int* __restrict__ tlo,
                                                     const int* __restrict__ thi,
                                                     int* __restrict__ knn) {
    const int lane = threadIdx.x & 63;
    const int wv   = threadIdx.x >> 6;
    const int s    = blockIdx.x * 4 + wv;   // sorted slot = this wave's query
    const int tq   = s >> 8;
    const int sl   = (s & 255) >> 2;        // self lane
    const int slot = s & 3;                 // self slot within lane

    const float* qp = stile + tq*1280 + (s & 255);
    const float qx = qp[0], qy = qp[256], qz = qp[512], qw = qp[768];
    const int   qi = reinterpret_cast<const int*>(qp)[1024];
    const f32x2 qx2 = {qx,qx}, qy2 = {qy,qy}, qz2 = {qz,qz}, qw2 = {qw,qw};

    const float* lbase = stile + lane*4;
    const bool is_self_lane = (lane == sl);

    // ---- pass 1: lane minima over the 5-tile x-window (disjoint candidate sets) ----
    float mn = INFF;
    int lo = tq - 2; if (lo < 0) lo = 0; if (lo > 27) lo = 27;
    #pragma unroll
    for (int tt = 0; tt < 5; ++tt) {
        const int t = lo + tt;
        const float* tp = lbase + t*1280;
        float4 X = *(const float4*)(tp);
        float4 Y = *(const float4*)(tp + 256);
        float4 Z = *(const float4*)(tp + 512);
        float4 S = *(const float4*)(tp + 768);
        f32x2 x01 = {X.x,X.y}, x23 = {X.z,X.w};
        f32x2 y01 = {Y.x,Y.y}, y23 = {Y.z,Y.w};
        f32x2 z01 = {Z.x,Z.y}, z23 = {Z.z,Z.w};
        f32x2 s01 = {S.x,S.y}, s23 = {S.z,S.w};
        f32x2 d01, d23;
        dist4(qx2, qy2, qz2, qw2, x01, x23, y01, y23, z01, z23, s01, s23, d01, d23);
        if ((t == tq) && is_self_lane) {
            if      (slot == 0) d01[0] = INFF;
            else if (slot == 1) d01[1] = INFF;
            else if (slot == 2) d23[0] = INFF;
            else                d23[1] = INFF;
        }
        mn = fminf(mn, fminf(fminf(d01[0], d01[1]), fminf(d23[0], d23[1])));
    }

    // ---- T = exact 16th smallest of the 64 lane minima (radix-select) ----
    float T;
    {
        unsigned x = __float_as_uint(mn);
        unsigned ub = ((int)x < 0) ? ~x : (x | 0x80000000u);
        unsigned long long alive = ~0ull;
        int need = KNN;
        for (int b = 31; b >= 0; --b) {
            unsigned long long ones  = __ballot(((ub >> b) & 1u) != 0u);
            unsigned long long zeros = alive & ~ones;
            int cz = (int)__popcll(zeros);
            bool tz = (cz >= need);
            alive = tz ? zeros : (alive & ones);
            need  = tz ? need : (need - cz);
        }
        T = fmaxf(rdlane_f(mn, (int)__ffsll(alive) - 1), 0.f);  // clamp: skip-bound safety
    }

    // ---- visit mask in registers (one coalesced tlo/thi read, no per-tile loads) ----
    unsigned mask;
    {
        const int ti = lane & 31;
        const int bl = tlo[ti], bh = thi[ti];
        const float xlo = (bl == 0)   ? -1e30f : (bl * 0.03125f - 4.0f);
        const float xhi = (bh == 255) ?  1e30f : ((bh + 1) * 0.03125f - 4.0f);
        float gap = fmaxf(0.f, fmaxf(xlo - qx, qx - xhi));
        bool gate = (gap * gap <= T + 1e-3f);   // margin >> all fp32 rounding
        mask = (unsigned)__ballot(gate && (lane < 32));
    }

    // ---- pass 2: iterate surviving tiles from the register mask ----
    float ld = INFF;
    int   li = -1;
    float Tl = INFF;

    while (mask) {
        const int t = (int)__ffs(mask) - 1;
        mask &= mask - 1;
        const float* tp = lbase + t*1280;
        float4 X = *(const float4*)(tp);
        float4 Y = *(const float4*)(tp + 256);
        float4 Z = *(const float4*)(tp + 512);
        float4 S = *(const float4*)(tp + 768);
        int4   I = *(const int4*)(tp + 1024);
        f32x2 x01 = {X.x,X.y}, x23 = {X.z,X.w};
        f32x2 y01 = {Y.x,Y.y}, y23 = {Y.z,Y.w};
        f32x2 z01 = {Z.x,Z.y}, z23 = {Z.z,Z.w};
        f32x2 s01 = {S.x,S.y}, s23 = {S.z,S.w};
        f32x2 d01, d23;
        dist4(qx2, qy2, qz2, qw2, x01, x23, y01, y23, z01, z23, s01, s23, d01, d23);
        if ((t == tq) && is_self_lane) {
            if      (slot == 0) d01[0] = INFF;
            else if (slot == 1) d01[1] = INFF;
            else if (slot == 2) d23[0] = INFF;
            else                d23[1] = INFF;
        }
        float tmin = fminf(fminf(d01[0], d01[1]), fminf(d23[0], d23[1]));
        if (__ballot(tmin <= T)) {
            insert16p(d01[0], I.x, T, ld, li, Tl, lane);
            insert16p(d01[1], I.y, T, ld, li, Tl, lane);
            insert16p(d23[0], I.z, T, ld, li, Tl, lane);
            insert16p(d23[1], I.w, T, ld, li, Tl, lane);
        }
    }

    if (lane < KNN) knn[qi*KNN + lane] = li;
}

// ---------------- GEMM: Ub/Vb[N][384] = Xb @ Wpt^T (+ b1 on U), bf16 out ----------------
// 1 wave per block, 64 rows x 64 cols; C/D: col = lane&15, row = (lane>>4)*4 + q

__global__ void __launch_bounds__(64) gemm_kernel(const __hip_bfloat16* __restrict__ Xb,
                                                  const __hip_bfloat16* __restrict__ Wpt,
                                                  const float* __restrict__ b1,
                                                  __hip_bfloat16* __restrict__ Ub,
                                                  __hip_bfloat16* __restrict__ Vb) {
    const int lane = threadIdx.x;
    const int i0   = blockIdx.x * 64;
    const int f0   = blockIdx.y * 64;
    const int lm   = lane & 15;
    const int lk   = (lane >> 4) * 8;

    f32x4 acc[4][4];
    #pragma unroll
    for (int r = 0; r < 4; ++r)
        #pragma unroll
        for (int c = 0; c < 4; ++c)
            acc[r][c] = (f32x4){0.f, 0.f, 0.f, 0.f};

    const __hip_bfloat16* xbase = Xb  + (size_t)(i0 + lm) * KP + lk;
    const __hip_bfloat16* wbase = Wpt + (size_t)(f0 + lm) * KP + lk;

    #pragma unroll
    for (int kk = 0; kk < 13; ++kk) {
        short8 a[4], b[4];
        #pragma unroll
        for (int r = 0; r < 4; ++r)
            a[r] = *reinterpret_cast<const short8*>(xbase + (size_t)r*16*KP + kk*32);
        #pragma unroll
        for (int c = 0; c < 4; ++c)
            b[c] = *reinterpret_cast<const short8*>(wbase + (size_t)c*16*KP + kk*32);
        #pragma unroll
        for (int r = 0; r < 4; ++r)
            #pragma unroll
            for (int c = 0; c < 4; ++c)
                acc[r][c] = __builtin_amdgcn_mfma_f32_16x16x32_bf16(a[r], b[c], acc[r][c], 0, 0, 0);
    }

    const bool isU = (f0 < TD);
    __hip_bfloat16* outb = isU ? (Ub + f0) : (Vb + (f0 - TD));
    float bias[4] = {0.f, 0.f, 0.f, 0.f};
    if (isU) {
        #pragma unroll
        for (int c = 0; c < 4; ++c) bias[c] = b1[f0 + c*16 + lm];
    }
    const int crow = (lane >> 4) * 4;
    #pragma unroll
    for (int r = 0; r < 4; ++r)
        #pragma unroll
        for (int c = 0; c < 4; ++c)
            #pragma unroll
            for (int q = 0; q < 4; ++q)
                outb[(size_t)(i0 + r*16 + crow + q) * TD + c*16 + lm] =
                    __float2bfloat16(acc[r][c][q] + bias[c]);
}

// ---------------- final: dim-parallel (lane owns 6 dims), coalesced row reads ----------------
// Validated round 11: depth-2 batch pipeline, buffered partials, pipelined DPP reduce.

__device__ __forceinline__ float bflo(unsigned w) { return __uint_as_float(w << 16); }
__device__ __forceinline__ float bfhi(unsigned w) { return __uint_as_float(w & 0xFFFF0000u); }

template<int CTRL>
__device__ __forceinline__ float dppf(float v) {
    return __uint_as_float((unsigned)__builtin_amdgcn_update_dpp(
        0, (int)__float_as_uint(v), CTRL, 0xF, 0xF, true));
}

__global__ void __launch_bounds__(256) final_kernel(const __hip_bfloat16* __restrict__ Ub,
                                                    const __hip_bfloat16* __restrict__ Vb,
                                                    const int* __restrict__ knn,
                                                    const float* __restrict__ xyz,
                                                    const float* __restrict__ W2,
                                                    const float* __restrict__ b2,
                                                    float* __restrict__ out) {
    const int lane = threadIdx.x & 63;
    const int wv   = threadIdx.x >> 6;
    const int i    = blockIdx.x * 4 + wv;
    const int d0   = lane * 6;

    int jreg = knn[i*KNN + (lane & 15)];

    float u[6], w2l[6][3];
    {
        const unsigned* rowU = reinterpret_cast<const unsigned*>(Ub + (size_t)i * TD) + lane*3;
        unsigned a0 = rowU[0], a1 = rowU[1], a2 = rowU[2];
        u[0] = bflo(a0); u[1] = bfhi(a0);
        u[2] = bflo(a1); u[3] = bfhi(a1);
        u[4] = bflo(a2); u[5] = bfhi(a2);
    }
    #pragma unroll
    for (int t = 0; t < 6; ++t)
        #pragma unroll
        for (int c = 0; c < 3; ++c) w2l[t][c] = W2[(d0 + t)*3 + c];

    const unsigned* vbase = reinterpret_cast<const unsigned*>(Vb);
    const int voff = lane * 3;

    float pk0[16], pk1[16], pk2[16];
    unsigned va[2][4][3];

    #pragma unroll
    for (int t = 0; t < 4; ++t) {
        int j = __builtin_amdgcn_readlane(jreg, t);
        const unsigned* rv = vbase + (size_t)j * 192 + voff;
        va[0][t][0] = rv[0]; va[0][t][1] = rv[1]; va[0][t][2] = rv[2];
    }
    __builtin_amdgcn_sched_barrier(0);

    #pragma unroll
    for (int b = 0; b < 4; ++b) {
        if (b < 3) {
            #pragma unroll
            for (int t = 0; t < 4; ++t) {
                int j = __builtin_amdgcn_readlane(jreg, (b+1)*4 + t);
                const unsigned* rv = vbase + (size_t)j * 192 + voff;
                va[(b+1)&1][t][0] = rv[0];
                va[(b+1)&1][t][1] = rv[1];
                va[(b+1)&1][t][2] = rv[2];
            }
            __builtin_amdgcn_sched_barrier(0);
        }
        #pragma unroll
        for (int t = 0; t < 4; ++t) {
            const int kk = b*4 + t;
            unsigned a0 = va[b&1][t][0], a1 = va[b&1][t][1], a2 = va[b&1][t][2];
            float v0 = bflo(a0), v1 = bfhi(a0);
            float v2 = bflo(a1), v3 = bfhi(a1);
            float v4 = bflo(a2), v5 = bfhi(a2);
            float h0 = fmaxf(u[0] + v0, 0.f), h1 = fmaxf(u[1] + v1, 0.f);
            float h2 = fmaxf(u[2] + v2, 0.f), h3 = fmaxf(u[3] + v3, 0.f);
            float h4 = fmaxf(u[4] + v4, 0.f), h5 = fmaxf(u[5] + v5, 0.f);
            float s0 = 0.f, s1 = 0.f, s2 = 0.f;
            s0 = fmaf(h0, w2l[0][0], s0); s1 = fmaf(h0, w2l[0][1], s1); s2 = fmaf(h0, w2l[0][2], s2);
            s0 = fmaf(h1, w2l[1][0], s0); s1 = fmaf(h1, w2l[1][1], s1); s2 = fmaf(h1, w2l[1][2], s2);
            s0 = fmaf(h2, w2l[2][0], s0); s1 = fmaf(h2, w2l[2][1], s1); s2 = fmaf(h2, w2l[2][2], s2);
            s0 = fmaf(h3, w2l[3][0], s0); s1 = fmaf(h3, w2l[3][1], s1); s2 = fmaf(h3, w2l[3][2], s2);
            s0 = fmaf(h4, w2l[4][0], s0); s1 = fmaf(h4, w2l[4][1], s1); s2 = fmaf(h4, w2l[4][2], s2);
            s0 = fmaf(h5, w2l[5][0], s0); s1 = fmaf(h5, w2l[5][1], s1); s2 = fmaf(h5, w2l[5][2], s2);
            pk0[kk] = s0; pk1[kk] = s1; pk2[kk] = s2;
        }
    }

    #pragma unroll
    for (int kk = 0; kk < 16; ++kk) {
        float r0 = pk0[kk], r1 = pk1[kk], r2 = pk2[kk];
        r0 += dppf<0x121>(r0); r1 += dppf<0x121>(r1); r2 += dppf<0x121>(r2);
        r0 += dppf<0x122>(r0); r1 += dppf<0x122>(r1); r2 += dppf<0x122>(r2);
        r0 += dppf<0x124>(r0); r1 += dppf<0x124>(r1); r2 += dppf<0x124>(r2);
        r0 += dppf<0x128>(r0); r1 += dppf<0x128>(r1); r2 += dppf<0x128>(r2);
        r0 += __shfl_xor(r0, 16); r1 += __shfl_xor(r1, 16); r2 += __shfl_xor(r2, 16);
        r0 += __shfl_xor(r0, 32); r1 += __shfl_xor(r1, 32); r2 += __shfl_xor(r2, 32);
        pk0[kk] = r0; pk1[kk] = r1; pk2[kk] = r2;
    }
    float mx0 = pk0[0], mx1 = pk1[0], mx2 = pk2[0];
    #pragma unroll
    for (int kk = 1; kk < 16; ++kk) {
        mx0 = fmaxf(mx0, pk0[kk]);
        mx1 = fmaxf(mx1, pk1[kk]);
        mx2 = fmaxf(mx2, pk2[kk]);
    }

    if (lane == 0) {
        out[i*3+0] = xyz[i*3+0] + mx0 + b2[0];
        out[i*3+1] = xyz[i*3+1] + mx1 + b2[1];
        out[i*3+2] = xyz[i*3+2] + mx2 + b2[2];
    }
}

// ---------------- launch ----------------

extern "C" void kernel_launch(void* const* d_in, const int* in_sizes, int n_in,
                              void* d_out, int out_size, void* d_ws, size_t ws_size,
                              hipStream_t stream) {
    const float* xyz  = (const float*)d_in[0];
    const float* feat = (const float*)d_in[1];
    const float* W1   = (const float*)d_in[2];
    const float* b1   = (const float*)d_in[3];
    const float* W2   = (const float*)d_in[4];
    const float* b2   = (const float*)d_in[5];
    float* out = (float*)d_out;

    char* ws = (char*)d_ws;
    int*            knn   = (int*)(ws + 0);                   //   524288 B
    float*          stile = (float*)(ws + 524288);            //   163840 B
    __hip_bfloat16* Xb    = (__hip_bfloat16*)(ws + 688128);   //  6815744 B
    __hip_bfloat16* Wpt   = (__hip_bfloat16*)(ws + 7503872);  //   638976 B
    __hip_bfloat16* Ub    = (__hip_bfloat16*)(ws + 8142848);  //  6291456 B
    __hip_bfloat16* Vb    = (__hip_bfloat16*)(ws + 14434304); //  6291456 B
    int*            hist  = (int*)(ws + 20725760);            //     1024 B
    int*            cut   = (int*)(ws + 20726784);            //     1024 B
    int*            thi   = (int*)(ws + 20727808);            //      128 B
    int*            tlo   = (int*)(ws + 20727936);            //      128 B -> end 20728064

    // init: hist/cut/thi = 0 (one contiguous region), tlo = 0x7F7F7F7F (> 255)
    hipMemsetAsync(hist, 0, 2176, stream);
    hipMemsetAsync(tlo, 0x7F, 128, stream);

    prep_all     <<<dim3(N + NF),      dim3(128), 0, stream>>>(feat, xyz, W1, Xb, Wpt, hist);
    assign_kernel<<<dim3(N/256),       dim3(256), 0, stream>>>(xyz, hist, cut, tlo, thi, stile);
    knn_kernel   <<<dim3(N/4),         dim3(256), 0, stream>>>(stile, tlo, thi, knn);
    gemm_kernel  <<<dim3(N/64, NF/64), dim3(64),  0, stream>>>(Xb, Wpt, b1, Ub, Vb);
    final_kernel <<<dim3(N/4),         dim3(256), 0, stream>>>(Ub, Vb, knn, xyz, W2, b2, out);
}

// Round 15
// 87.368 us; speedup vs baseline: 1.3992x; 1.2613x over previous
//
#include <hip/hip_runtime.h>
#include <hip/hip_bf16.h>

// GNNRefiner: out = xyz + max_k( relu([x_i, x_j-x_i]·W1 + b1)·W2 + b2 )
// Factorization: e·W1 = x_i·(A-B) + x_j·B  with A=W1[0:387], B=W1[387:774].
// Pipeline (5 dispatches, no memsets): prep(+cut init block) -> assign(per-block full
//           hist + scan + bounds + scatter) -> knn (1 query/wave, 5-tile pass-1 T,
//           register-mask pruned pass-2) -> bf16 MFMA GEMM (+b1) -> final (r11).
// KNN pruning: tile skipped iff gap^2 > T + 1e-3 (gap = x-gap to tile bin range);
// T = 16th-smallest of 64 disjoint-set lane minima (provable D16 upper bound).

#define N 8192
#define TD 384      // TOKEN_DIM
#define KNN 16
#define DX 387      // TD + 3
#define KP 416      // DX padded to multiple of 32
#define NF 768      // 2*TD output cols of fused GEMM
#define INFF __builtin_inff()

typedef __attribute__((ext_vector_type(8))) short short8;
typedef __attribute__((ext_vector_type(4))) float f32x4;
typedef __attribute__((ext_vector_type(2))) float f32x2;

// ---------------- packed fp32 helpers (bit-identical to scalar ops, 2 cands/instr) ----------------

__device__ __forceinline__ f32x2 pk_mul(f32x2 a, f32x2 b) {
    f32x2 r; asm("v_pk_mul_f32 %0, %1, %2" : "=v"(r) : "v"(a), "v"(b)); return r;
}
__device__ __forceinline__ f32x2 pk_add(f32x2 a, f32x2 b) {
    f32x2 r; asm("v_pk_add_f32 %0, %1, %2" : "=v"(r) : "v"(a), "v"(b)); return r;
}
__device__ __forceinline__ f32x2 pk_sub(f32x2 a, f32x2 b) {  // a - b, same rounding as fsub
    f32x2 r; asm("v_pk_add_f32 %0, %1, %2 neg_lo:[0,1] neg_hi:[0,1]" : "=v"(r) : "v"(a), "v"(b)); return r;
}
__device__ __forceinline__ f32x2 pk_fma(f32x2 a, f32x2 b, f32x2 c) {
    f32x2 r; asm("v_pk_fma_f32 %0, %1, %2, %3" : "=v"(r) : "v"(a), "v"(b), "v"(c)); return r;
}

// d2 = (qw + sq_j) - 2*dot, dot = fma(qz,z, fma(qy,y, mul(qx,x)))  [bit-identical to ref]
__device__ __forceinline__ void dist4(f32x2 qx, f32x2 qy, f32x2 qz, f32x2 qw,
                                      f32x2 x01, f32x2 x23, f32x2 y01, f32x2 y23,
                                      f32x2 z01, f32x2 z23, f32x2 s01, f32x2 s23,
                                      f32x2& d01, f32x2& d23) {
    f32x2 dot01 = pk_fma(qz, z01, pk_fma(qy, y01, pk_mul(qx, x01)));
    f32x2 dot23 = pk_fma(qz, z23, pk_fma(qy, y23, pk_mul(qx, x23)));
    d01 = pk_sub(pk_add(qw, s01), pk_add(dot01, dot01));  // dot+dot == 2*dot exactly
    d23 = pk_sub(pk_add(qw, s23), pk_add(dot23, dot23));
}

// x-sort bin (identical expression everywhere -> deterministic)
__device__ __forceinline__ int xbin(float x) {
    int b = (int)((x + 4.0f) * 32.0f);
    return b < 0 ? 0 : (b > 255 ? 255 : b);
}

// ---------------- prep: Xb rows + Wpt; LAST block zeroes the cut cursor ----------------

__global__ void __launch_bounds__(128) prep_all(const float* __restrict__ feat,
                                                const float* __restrict__ xyz,
                                                const float* __restrict__ W1,
                                                __hip_bfloat16* __restrict__ Xb,
                                                __hip_bfloat16* __restrict__ Wpt,
                                                int* __restrict__ cut) {
    int b = blockIdx.x;
    int t = threadIdx.x;
    if (b < N) {
        if (t < 96) {  // vectorized feat copy: 96 x float4 -> 4 x bf16
            float4 f = reinterpret_cast<const float4*>(feat + (size_t)b*TD)[t];
            __hip_bfloat16 h[4] = {__float2bfloat16(f.x), __float2bfloat16(f.y),
                                   __float2bfloat16(f.z), __float2bfloat16(f.w)};
            *reinterpret_cast<ulonglong1*>(Xb + b*KP + t*4) = *reinterpret_cast<ulonglong1*>(h);
        } else if (t == 96) {  // xyz tail + zero pad
            for (int d = TD; d < KP; ++d) {
                float v = (d < DX) ? xyz[b*3 + (d - TD)] : 0.f;
                Xb[b*KP + d] = __float2bfloat16(v);
            }
        }
    } else if (b < N + NF) {
        int f = b - N;  // 0..767
        for (int k = t; k < KP; k += 128) {
            float v = 0.f;
            if (k < DX) {
                if (f < TD) v = W1[k*TD + f] - W1[(DX+k)*TD + f];
                else        v = W1[(DX+k)*TD + (f - TD)];
            }
            Wpt[f*KP + k] = __float2bfloat16(v);
        }
    } else {           // init block: zero the 256-entry cut cursor (runs before assign)
        cut[t] = 0;
        cut[t + 128] = 0;
    }
}

// ---------------- assign: 32 blocks; per-block full hist + scan + bounds + scatter ----------------
// sorted tiles: per 256-slot tile: [x(256)|y(256)|z(256)|sq(256)|idx(256)] (5120B)
// Hist/scan are deterministic (identical in every block); slot order within a bin is
// atomic-nondeterministic but output-invariant (selection is exact top-16 by (d, orig idx);
// tile bin-ranges cover whichever points land in the tile).

__global__ void __launch_bounds__(256) assign_kernel(const float* __restrict__ xyz,
                                                     int* __restrict__ cut,
                                                     int* __restrict__ tlo,
                                                     int* __restrict__ thi,
                                                     float* __restrict__ stile) {
    __shared__ int hcnt[256];
    __shared__ int base[256];
    __shared__ int stlo[32], sthi[32];
    const int t = threadIdx.x;

    hcnt[t] = 0;
    if (t < 32) { stlo[t] = 255; sthi[t] = 0; }
    __syncthreads();

    // full histogram (all blocks compute identically; 8192 x-reads, L2-hot)
    #pragma unroll
    for (int c = 0; c < 32; ++c) {
        atomicAdd(&hcnt[xbin(xyz[(t + c*256)*3])], 1);
    }
    __syncthreads();

    const int v = hcnt[t];
    base[t] = v;
    __syncthreads();
    for (int off = 1; off < 256; off <<= 1) {
        int add = (t >= off) ? base[t - off] : 0;
        __syncthreads();
        base[t] += add;
        __syncthreads();
    }
    const int end = base[t], start = end - v;   // inclusive / exclusive prefix
    __syncthreads();
    base[t] = start;
    __syncthreads();

    if (blockIdx.x == 0) {   // per-tile conservative bin range, direct write (no global init)
        if (v > 0) {
            for (int x = start >> 8; x <= (end - 1) >> 8; ++x) {
                atomicMin(&stlo[x], t);
                atomicMax(&sthi[x], t);
            }
        }
        __syncthreads();
        if (t < 32) { tlo[t] = stlo[t]; thi[t] = sthi[t]; }
    }

    // scatter this block's 256 points
    const int i = blockIdx.x * 256 + t;
    float x = xyz[i*3+0], y = xyz[i*3+1], z = xyz[i*3+2];
    int bin = xbin(x);
    int pos = base[bin] + atomicAdd(&cut[bin], 1);
    float sq = __fadd_rn(__fadd_rn(__fmul_rn(x,x), __fmul_rn(y,y)), __fmul_rn(z,z));
    float* tp = stile + (pos >> 8) * 1280 + (pos & 255);
    tp[0] = x; tp[256] = y; tp[512] = z; tp[768] = sq;
    reinterpret_cast<int*>(tp)[1024] = i;
}

// ---------------- knn helpers ----------------

__device__ __forceinline__ float dpp_shr1_f(float v) {
    return __uint_as_float((unsigned)__builtin_amdgcn_update_dpp(
        (int)__float_as_uint(v), (int)__float_as_uint(v), 0x111, 0xF, 0xF, false));
}
__device__ __forceinline__ int dpp_shr1_i(int v) {
    return __builtin_amdgcn_update_dpp(v, v, 0x111, 0xF, 0xF, false);
}
__device__ __forceinline__ float rdlane_f(float v, int src) {
    return __uint_as_float(__builtin_amdgcn_readlane(__float_as_uint(v), src));
}

// Sorted-by-lane top-16 insert with per-candidate orig-idx payload.
__device__ __forceinline__ void insert16p(float dv, int cjv, float Tq,
                                          float& ld, int& li, float& Tl, int lane) {
    unsigned long long m = __ballot((dv <= Tq) && (dv < Tl));
    while (m) {
        int src = (int)__ffsll(m) - 1;
        float cd = rdlane_f(dv, src);
        int   cj = __builtin_amdgcn_readlane(cjv, src);
        bool lt = (ld < cd) || (ld == cd && li < cj);
        int pos = (int)__popcll(__ballot(lt) & 0xFFFFull);
        float ud = dpp_shr1_f(ld);
        int   ui = dpp_shr1_i(li);
        ld = (lane == pos) ? cd : ((lane > pos) ? ud : ld);
        li = (lane == pos) ? cj : ((lane > pos) ? ui : li);
        Tl = rdlane_f(ld, 15);
        m &= ~(1ull << src);
        m &= __ballot(dv < Tl);
    }
}

// ---------------- knn: ONE query per wave; full 5-tile pass-1; mask-pruned pass-2 ----------------

__global__ void __launch_bounds__(256, 8) knn_kernel(const float* __restrict__ stile,
                                                     const int* __restrict__ tlo,
                                                     const int* __restrict__ thi,
                                                     int* __restrict__ knn) {
    const int lane = threadIdx.x & 63;
    const int wv   = threadIdx.x >> 6;
    const int s    = blockIdx.x * 4 + wv;   // sorted slot = this wave's query
    const int tq   = s >> 8;
    const int sl   = (s & 255) >> 2;        // self lane
    const int slot = s & 3;                 // self slot within lane

    const float* qp = stile + tq*1280 + (s & 255);
    const float qx = qp[0], qy = qp[256], qz = qp[512], qw = qp[768];
    const int   qi = reinterpret_cast<const int*>(qp)[1024];
    const f32x2 qx2 = {qx,qx}, qy2 = {qy,qy}, qz2 = {qz,qz}, qw2 = {qw,qw};

    const float* lbase = stile + lane*4;
    const bool is_self_lane = (lane == sl);

    // ---- pass 1: lane minima over the 5-tile x-window (disjoint candidate sets) ----
    float mn = INFF;
    int lo = tq - 2; if (lo < 0) lo = 0; if (lo > 27) lo = 27;
    #pragma unroll
    for (int tt = 0; tt < 5; ++tt) {
        const int t = lo + tt;
        const float* tp = lbase + t*1280;
        float4 X = *(const float4*)(tp);
        float4 Y = *(const float4*)(tp + 256);
        float4 Z = *(const float4*)(tp + 512);
        float4 S = *(const float4*)(tp + 768);
        f32x2 x01 = {X.x,X.y}, x23 = {X.z,X.w};
        f32x2 y01 = {Y.x,Y.y}, y23 = {Y.z,Y.w};
        f32x2 z01 = {Z.x,Z.y}, z23 = {Z.z,Z.w};
        f32x2 s01 = {S.x,S.y}, s23 = {S.z,S.w};
        f32x2 d01, d23;
        dist4(qx2, qy2, qz2, qw2, x01, x23, y01, y23, z01, z23, s01, s23, d01, d23);
        if ((t == tq) && is_self_lane) {
            if      (slot == 0) d01[0] = INFF;
            else if (slot == 1) d01[1] = INFF;
            else if (slot == 2) d23[0] = INFF;
            else                d23[1] = INFF;
        }
        mn = fminf(mn, fminf(fminf(d01[0], d01[1]), fminf(d23[0], d23[1])));
    }

    // ---- T = exact 16th smallest of the 64 lane minima (radix-select) ----
    float T;
    {
        unsigned x = __float_as_uint(mn);
        unsigned ub = ((int)x < 0) ? ~x : (x | 0x80000000u);
        unsigned long long alive = ~0ull;
        int need = KNN;
        for (int b = 31; b >= 0; --b) {
            unsigned long long ones  = __ballot(((ub >> b) & 1u) != 0u);
            unsigned long long zeros = alive & ~ones;
            int cz = (int)__popcll(zeros);
            bool tz = (cz >= need);
            alive = tz ? zeros : (alive & ones);
            need  = tz ? need : (need - cz);
        }
        T = fmaxf(rdlane_f(mn, (int)__ffsll(alive) - 1), 0.f);  // clamp: skip-bound safety
    }

    // ---- visit mask in registers (one coalesced tlo/thi read, no per-tile loads) ----
    unsigned mask;
    {
        const int ti = lane & 31;
        const int bl = tlo[ti], bh = thi[ti];
        const float xlo = (bl == 0)   ? -1e30f : (bl * 0.03125f - 4.0f);
        const float xhi = (bh == 255) ?  1e30f : ((bh + 1) * 0.03125f - 4.0f);
        float gap = fmaxf(0.f, fmaxf(xlo - qx, qx - xhi));
        bool gate = (gap * gap <= T + 1e-3f);   // margin >> all fp32 rounding
        mask = (unsigned)__ballot(gate && (lane < 32));
    }

    // ---- pass 2: iterate surviving tiles from the register mask ----
    float ld = INFF;
    int   li = -1;
    float Tl = INFF;

    while (mask) {
        const int t = (int)__ffs(mask) - 1;
        mask &= mask - 1;
        const float* tp = lbase + t*1280;
        float4 X = *(const float4*)(tp);
        float4 Y = *(const float4*)(tp + 256);
        float4 Z = *(const float4*)(tp + 512);
        float4 S = *(const float4*)(tp + 768);
        int4   I = *(const int4*)(tp + 1024);
        f32x2 x01 = {X.x,X.y}, x23 = {X.z,X.w};
        f32x2 y01 = {Y.x,Y.y}, y23 = {Y.z,Y.w};
        f32x2 z01 = {Z.x,Z.y}, z23 = {Z.z,Z.w};
        f32x2 s01 = {S.x,S.y}, s23 = {S.z,S.w};
        f32x2 d01, d23;
        dist4(qx2, qy2, qz2, qw2, x01, x23, y01, y23, z01, z23, s01, s23, d01, d23);
        if ((t == tq) && is_self_lane) {
            if      (slot == 0) d01[0] = INFF;
            else if (slot == 1) d01[1] = INFF;
            else if (slot == 2) d23[0] = INFF;
            else                d23[1] = INFF;
        }
        float tmin = fminf(fminf(d01[0], d01[1]), fminf(d23[0], d23[1]));
        if (__ballot(tmin <= T)) {
            insert16p(d01[0], I.x, T, ld, li, Tl, lane);
            insert16p(d01[1], I.y, T, ld, li, Tl, lane);
            insert16p(d23[0], I.z, T, ld, li, Tl, lane);
            insert16p(d23[1], I.w, T, ld, li, Tl, lane);
        }
    }

    if (lane < KNN) knn[qi*KNN + lane] = li;
}

// ---------------- GEMM: Ub/Vb[N][384] = Xb @ Wpt^T (+ b1 on U), bf16 out ----------------
// 1 wave per block, 64 rows x 64 cols; C/D: col = lane&15, row = (lane>>4)*4 + q

__global__ void __launch_bounds__(64) gemm_kernel(const __hip_bfloat16* __restrict__ Xb,
                                                  const __hip_bfloat16* __restrict__ Wpt,
                                                  const float* __restrict__ b1,
                                                  __hip_bfloat16* __restrict__ Ub,
                                                  __hip_bfloat16* __restrict__ Vb) {
    const int lane = threadIdx.x;
    const int i0   = blockIdx.x * 64;
    const int f0   = blockIdx.y * 64;
    const int lm   = lane & 15;
    const int lk   = (lane >> 4) * 8;

    f32x4 acc[4][4];
    #pragma unroll
    for (int r = 0; r < 4; ++r)
        #pragma unroll
        for (int c = 0; c < 4; ++c)
            acc[r][c] = (f32x4){0.f, 0.f, 0.f, 0.f};

    const __hip_bfloat16* xbase = Xb  + (size_t)(i0 + lm) * KP + lk;
    const __hip_bfloat16* wbase = Wpt + (size_t)(f0 + lm) * KP + lk;

    #pragma unroll
    for (int kk = 0; kk < 13; ++kk) {
        short8 a[4], b[4];
        #pragma unroll
        for (int r = 0; r < 4; ++r)
            a[r] = *reinterpret_cast<const short8*>(xbase + (size_t)r*16*KP + kk*32);
        #pragma unroll
        for (int c = 0; c < 4; ++c)
            b[c] = *reinterpret_cast<const short8*>(wbase + (size_t)c*16*KP + kk*32);
        #pragma unroll
        for (int r = 0; r < 4; ++r)
            #pragma unroll
            for (int c = 0; c < 4; ++c)
                acc[r][c] = __builtin_amdgcn_mfma_f32_16x16x32_bf16(a[r], b[c], acc[r][c], 0, 0, 0);
    }

    const bool isU = (f0 < TD);
    __hip_bfloat16* outb = isU ? (Ub + f0) : (Vb + (f0 - TD));
    float bias[4] = {0.f, 0.f, 0.f, 0.f};
    if (isU) {
        #pragma unroll
        for (int c = 0; c < 4; ++c) bias[c] = b1[f0 + c*16 + lm];
    }
    const int crow = (lane >> 4) * 4;
    #pragma unroll
    for (int r = 0; r < 4; ++r)
        #pragma unroll
        for (int c = 0; c < 4; ++c)
            #pragma unroll
            for (int q = 0; q < 4; ++q)
                outb[(size_t)(i0 + r*16 + crow + q) * TD + c*16 + lm] =
                    __float2bfloat16(acc[r][c][q] + bias[c]);
}

// ---------------- final: dim-parallel (lane owns 6 dims), coalesced row reads ----------------
// Validated round 11: depth-2 batch pipeline, buffered partials, pipelined DPP reduce.

__device__ __forceinline__ float bflo(unsigned w) { return __uint_as_float(w << 16); }
__device__ __forceinline__ float bfhi(unsigned w) { return __uint_as_float(w & 0xFFFF0000u); }

template<int CTRL>
__device__ __forceinline__ float dppf(float v) {
    return __uint_as_float((unsigned)__builtin_amdgcn_update_dpp(
        0, (int)__float_as_uint(v), CTRL, 0xF, 0xF, true));
}

__global__ void __launch_bounds__(256) final_kernel(const __hip_bfloat16* __restrict__ Ub,
                                                    const __hip_bfloat16* __restrict__ Vb,
                                                    const int* __restrict__ knn,
                                                    const float* __restrict__ xyz,
                                                    const float* __restrict__ W2,
                                                    const float* __restrict__ b2,
                                                    float* __restrict__ out) {
    const int lane = threadIdx.x & 63;
    const int wv   = threadIdx.x >> 6;
    const int i    = blockIdx.x * 4 + wv;
    const int d0   = lane * 6;

    int jreg = knn[i*KNN + (lane & 15)];

    float u[6], w2l[6][3];
    {
        const unsigned* rowU = reinterpret_cast<const unsigned*>(Ub + (size_t)i * TD) + lane*3;
        unsigned a0 = rowU[0], a1 = rowU[1], a2 = rowU[2];
        u[0] = bflo(a0); u[1] = bfhi(a0);
        u[2] = bflo(a1); u[3] = bfhi(a1);
        u[4] = bflo(a2); u[5] = bfhi(a2);
    }
    #pragma unroll
    for (int t = 0; t < 6; ++t)
        #pragma unroll
        for (int c = 0; c < 3; ++c) w2l[t][c] = W2[(d0 + t)*3 + c];

    const unsigned* vbase = reinterpret_cast<const unsigned*>(Vb);
    const int voff = lane * 3;

    float pk0[16], pk1[16], pk2[16];
    unsigned va[2][4][3];

    #pragma unroll
    for (int t = 0; t < 4; ++t) {
        int j = __builtin_amdgcn_readlane(jreg, t);
        const unsigned* rv = vbase + (size_t)j * 192 + voff;
        va[0][t][0] = rv[0]; va[0][t][1] = rv[1]; va[0][t][2] = rv[2];
    }
    __builtin_amdgcn_sched_barrier(0);

    #pragma unroll
    for (int b = 0; b < 4; ++b) {
        if (b < 3) {
            #pragma unroll
            for (int t = 0; t < 4; ++t) {
                int j = __builtin_amdgcn_readlane(jreg, (b+1)*4 + t);
                const unsigned* rv = vbase + (size_t)j * 192 + voff;
                va[(b+1)&1][t][0] = rv[0];
                va[(b+1)&1][t][1] = rv[1];
                va[(b+1)&1][t][2] = rv[2];
            }
            __builtin_amdgcn_sched_barrier(0);
        }
        #pragma unroll
        for (int t = 0; t < 4; ++t) {
            const int kk = b*4 + t;
            unsigned a0 = va[b&1][t][0], a1 = va[b&1][t][1], a2 = va[b&1][t][2];
            float v0 = bflo(a0), v1 = bfhi(a0);
            float v2 = bflo(a1), v3 = bfhi(a1);
            float v4 = bflo(a2), v5 = bfhi(a2);
            float h0 = fmaxf(u[0] + v0, 0.f), h1 = fmaxf(u[1] + v1, 0.f);
            float h2 = fmaxf(u[2] + v2, 0.f), h3 = fmaxf(u[3] + v3, 0.f);
            float h4 = fmaxf(u[4] + v4, 0.f), h5 = fmaxf(u[5] + v5, 0.f);
            float s0 = 0.f, s1 = 0.f, s2 = 0.f;
            s0 = fmaf(h0, w2l[0][0], s0); s1 = fmaf(h0, w2l[0][1], s1); s2 = fmaf(h0, w2l[0][2], s2);
            s0 = fmaf(h1, w2l[1][0], s0); s1 = fmaf(h1, w2l[1][1], s1); s2 = fmaf(h1, w2l[1][2], s2);
            s0 = fmaf(h2, w2l[2][0], s0); s1 = fmaf(h2, w2l[2][1], s1); s2 = fmaf(h2, w2l[2][2], s2);
            s0 = fmaf(h3, w2l[3][0], s0); s1 = fmaf(h3, w2l[3][1], s1); s2 = fmaf(h3, w2l[3][2], s2);
            s0 = fmaf(h4, w2l[4][0], s0); s1 = fmaf(h4, w2l[4][1], s1); s2 = fmaf(h4, w2l[4][2], s2);
            s0 = fmaf(h5, w2l[5][0], s0); s1 = fmaf(h5, w2l[5][1], s1); s2 = fmaf(h5, w2l[5][2], s2);
            pk0[kk] = s0; pk1[kk] = s1; pk2[kk] = s2;
        }
    }

    #pragma unroll
    for (int kk = 0; kk < 16; ++kk) {
        float r0 = pk0[kk], r1 = pk1[kk], r2 = pk2[kk];
        r0 += dppf<0x121>(r0); r1 += dppf<0x121>(r1); r2 += dppf<0x121>(r2);
        r0 += dppf<0x122>(r0); r1 += dppf<0x122>(r1); r2 += dppf<0x122>(r2);
        r0 += dppf<0x124>(r0); r1 += dppf<0x124>(r1); r2 += dppf<0x124>(r2);
        r0 += dppf<0x128>(r0); r1 += dppf<0x128>(r1); r2 += dppf<0x128>(r2);
        r0 += __shfl_xor(r0, 16); r1 += __shfl_xor(r1, 16); r2 += __shfl_xor(r2, 16);
        r0 += __shfl_xor(r0, 32); r1 += __shfl_xor(r1, 32); r2 += __shfl_xor(r2, 32);
        pk0[kk] = r0; pk1[kk] = r1; pk2[kk] = r2;
    }
    float mx0 = pk0[0], mx1 = pk1[0], mx2 = pk2[0];
    #pragma unroll
    for (int kk = 1; kk < 16; ++kk) {
        mx0 = fmaxf(mx0, pk0[kk]);
        mx1 = fmaxf(mx1, pk1[kk]);
        mx2 = fmaxf(mx2, pk2[kk]);
    }

    if (lane == 0) {
        out[i*3+0] = xyz[i*3+0] + mx0 + b2[0];
        out[i*3+1] = xyz[i*3+1] + mx1 + b2[1];
        out[i*3+2] = xyz[i*3+2] + mx2 + b2[2];
    }
}

// ---------------- launch ----------------

extern "C" void kernel_launch(void* const* d_in, const int* in_sizes, int n_in,
                              void* d_out, int out_size, void* d_ws, size_t ws_size,
                              hipStream_t stream) {
    const float* xyz  = (const float*)d_in[0];
    const float* feat = (const float*)d_in[1];
    const float* W1   = (const float*)d_in[2];
    const float* b1   = (const float*)d_in[3];
    const float* W2   = (const float*)d_in[4];
    const float* b2   = (const float*)d_in[5];
    float* out = (float*)d_out;

    char* ws = (char*)d_ws;
    int*            knn   = (int*)(ws + 0);                   //   524288 B
    float*          stile = (float*)(ws + 524288);            //   163840 B
    __hip_bfloat16* Xb    = (__hip_bfloat16*)(ws + 688128);   //  6815744 B
    __hip_bfloat16* Wpt   = (__hip_bfloat16*)(ws + 7503872);  //   638976 B
    __hip_bfloat16* Ub    = (__hip_bfloat16*)(ws + 8142848);  //  6291456 B
    __hip_bfloat16* Vb    = (__hip_bfloat16*)(ws + 14434304); //  6291456 B
    int*            cut   = (int*)(ws + 20725760);            //     1024 B
    int*            thi   = (int*)(ws + 20726784);            //      128 B
    int*            tlo   = (int*)(ws + 20726912);            //      128 B -> end 20727040

    prep_all     <<<dim3(N + NF + 1),  dim3(128), 0, stream>>>(feat, xyz, W1, Xb, Wpt, cut);
    assign_kernel<<<dim3(N/256),       dim3(256), 0, stream>>>(xyz, cut, tlo, thi, stile);
    knn_kernel   <<<dim3(N/4),         dim3(256), 0, stream>>>(stile, tlo, thi, knn);
    gemm_kernel  <<<dim3(N/64, NF/64), dim3(64),  0, stream>>>(Xb, Wpt, b1, Ub, Vb);
    final_kernel <<<dim3(N/4),         dim3(256), 0, stream>>>(Ub, Vb, knn, xyz, W2, b2, out);
}

// Round 16
// 85.957 us; speedup vs baseline: 1.4222x; 1.0164x over previous
//
#include <hip/hip_runtime.h>
#include <hip/hip_bf16.h>

// GNNRefiner: out = xyz + max_k( relu([x_i, x_j-x_i]·W1 + b1)·W2 + b2 )
// Factorization: e·W1 = x_i·(A-B) + x_j·B  with A=W1[0:387], B=W1[387:774].
// Pipeline (5 dispatches): prep(+cut init block) -> assign(per-block full hist + scan
//           + bounds + scatter) -> knn (1 query/wave, 5-tile pass-1 T, mask-pruned
//           pass-2 with BALLOT-PREFIX COMPACTION + radix top-16, no serial insert)
//           -> bf16 MFMA GEMM (+b1) -> final (dim-parallel, validated r11).
// KNN: T = 16th-smallest of 64 disjoint-set lane minima (provable D16 upper bound);
// tile skipped iff gap^2 > T + 1e-3; all candidates d<=T compacted to LDS, then one
// exact radix-select of the 16 smallest (d, idx) — set-identical to the reference
// (downstream max over k is order-invariant).

#define N 8192
#define TD 384      // TOKEN_DIM
#define KNN 16
#define DX 387      // TD + 3
#define KP 416      // DX padded to multiple of 32
#define NF 768      // 2*TD output cols of fused GEMM
#define INFF __builtin_inff()

typedef __attribute__((ext_vector_type(8))) short short8;
typedef __attribute__((ext_vector_type(4))) float f32x4;
typedef __attribute__((ext_vector_type(2))) float f32x2;

// ---------------- packed fp32 helpers (bit-identical to scalar ops, 2 cands/instr) ----------------

__device__ __forceinline__ f32x2 pk_mul(f32x2 a, f32x2 b) {
    f32x2 r; asm("v_pk_mul_f32 %0, %1, %2" : "=v"(r) : "v"(a), "v"(b)); return r;
}
__device__ __forceinline__ f32x2 pk_add(f32x2 a, f32x2 b) {
    f32x2 r; asm("v_pk_add_f32 %0, %1, %2" : "=v"(r) : "v"(a), "v"(b)); return r;
}
__device__ __forceinline__ f32x2 pk_sub(f32x2 a, f32x2 b) {  // a - b, same rounding as fsub
    f32x2 r; asm("v_pk_add_f32 %0, %1, %2 neg_lo:[0,1] neg_hi:[0,1]" : "=v"(r) : "v"(a), "v"(b)); return r;
}
__device__ __forceinline__ f32x2 pk_fma(f32x2 a, f32x2 b, f32x2 c) {
    f32x2 r; asm("v_pk_fma_f32 %0, %1, %2, %3" : "=v"(r) : "v"(a), "v"(b), "v"(c)); return r;
}

// d2 = (qw + sq_j) - 2*dot, dot = fma(qz,z, fma(qy,y, mul(qx,x)))  [bit-identical to ref]
__device__ __forceinline__ void dist4(f32x2 qx, f32x2 qy, f32x2 qz, f32x2 qw,
                                      f32x2 x01, f32x2 x23, f32x2 y01, f32x2 y23,
                                      f32x2 z01, f32x2 z23, f32x2 s01, f32x2 s23,
                                      f32x2& d01, f32x2& d23) {
    f32x2 dot01 = pk_fma(qz, z01, pk_fma(qy, y01, pk_mul(qx, x01)));
    f32x2 dot23 = pk_fma(qz, z23, pk_fma(qy, y23, pk_mul(qx, x23)));
    d01 = pk_sub(pk_add(qw, s01), pk_add(dot01, dot01));  // dot+dot == 2*dot exactly
    d23 = pk_sub(pk_add(qw, s23), pk_add(dot23, dot23));
}

// x-sort bin (identical expression everywhere -> deterministic)
__device__ __forceinline__ int xbin(float x) {
    int b = (int)((x + 4.0f) * 32.0f);
    return b < 0 ? 0 : (b > 255 ? 255 : b);
}

// ---------------- prep: Xb rows + Wpt; LAST block zeroes the cut cursor ----------------

__global__ void __launch_bounds__(128) prep_all(const float* __restrict__ feat,
                                                const float* __restrict__ xyz,
                                                const float* __restrict__ W1,
                                                __hip_bfloat16* __restrict__ Xb,
                                                __hip_bfloat16* __restrict__ Wpt,
                                                int* __restrict__ cut) {
    int b = blockIdx.x;
    int t = threadIdx.x;
    if (b < N) {
        if (t < 96) {  // vectorized feat copy: 96 x float4 -> 4 x bf16
            float4 f = reinterpret_cast<const float4*>(feat + (size_t)b*TD)[t];
            __hip_bfloat16 h[4] = {__float2bfloat16(f.x), __float2bfloat16(f.y),
                                   __float2bfloat16(f.z), __float2bfloat16(f.w)};
            *reinterpret_cast<ulonglong1*>(Xb + b*KP + t*4) = *reinterpret_cast<ulonglong1*>(h);
        } else if (t == 96) {  // xyz tail + zero pad
            for (int d = TD; d < KP; ++d) {
                float v = (d < DX) ? xyz[b*3 + (d - TD)] : 0.f;
                Xb[b*KP + d] = __float2bfloat16(v);
            }
        }
    } else if (b < N + NF) {
        int f = b - N;  // 0..767
        for (int k = t; k < KP; k += 128) {
            float v = 0.f;
            if (k < DX) {
                if (f < TD) v = W1[k*TD + f] - W1[(DX+k)*TD + f];
                else        v = W1[(DX+k)*TD + (f - TD)];
            }
            Wpt[f*KP + k] = __float2bfloat16(v);
        }
    } else {           // init block: zero the 256-entry cut cursor (runs before assign)
        cut[t] = 0;
        cut[t + 128] = 0;
    }
}

// ---------------- assign: 32 blocks; per-block full hist + scan + bounds + scatter ----------------
// sorted tiles: per 256-slot tile: [x(256)|y(256)|z(256)|sq(256)|idx(256)] (5120B)

__global__ void __launch_bounds__(256) assign_kernel(const float* __restrict__ xyz,
                                                     int* __restrict__ cut,
                                                     int* __restrict__ tlo,
                                                     int* __restrict__ thi,
                                                     float* __restrict__ stile) {
    __shared__ int hcnt[256];
    __shared__ int base[256];
    __shared__ int stlo[32], sthi[32];
    const int t = threadIdx.x;

    hcnt[t] = 0;
    if (t < 32) { stlo[t] = 255; sthi[t] = 0; }
    __syncthreads();

    // full histogram (all blocks compute identically; 8192 x-reads, L2-hot)
    #pragma unroll
    for (int c = 0; c < 32; ++c) {
        atomicAdd(&hcnt[xbin(xyz[(t + c*256)*3])], 1);
    }
    __syncthreads();

    const int v = hcnt[t];
    base[t] = v;
    __syncthreads();
    for (int off = 1; off < 256; off <<= 1) {
        int add = (t >= off) ? base[t - off] : 0;
        __syncthreads();
        base[t] += add;
        __syncthreads();
    }
    const int end = base[t], start = end - v;   // inclusive / exclusive prefix
    __syncthreads();
    base[t] = start;
    __syncthreads();

    if (blockIdx.x == 0) {   // per-tile conservative bin range, direct write
        if (v > 0) {
            for (int x = start >> 8; x <= (end - 1) >> 8; ++x) {
                atomicMin(&stlo[x], t);
                atomicMax(&sthi[x], t);
            }
        }
        __syncthreads();
        if (t < 32) { tlo[t] = stlo[t]; thi[t] = sthi[t]; }
    }

    // scatter this block's 256 points
    const int i = blockIdx.x * 256 + t;
    float x = xyz[i*3+0], y = xyz[i*3+1], z = xyz[i*3+2];
    int bin = xbin(x);
    int pos = base[bin] + atomicAdd(&cut[bin], 1);
    float sq = __fadd_rn(__fadd_rn(__fmul_rn(x,x), __fmul_rn(y,y)), __fmul_rn(z,z));
    float* tp = stile + (pos >> 8) * 1280 + (pos & 255);
    tp[0] = x; tp[256] = y; tp[512] = z; tp[768] = sq;
    reinterpret_cast<int*>(tp)[1024] = i;
}

// ---------------- knn helpers ----------------

__device__ __forceinline__ float rdlane_f(float v, int src) {
    return __uint_as_float(__builtin_amdgcn_readlane(__float_as_uint(v), src));
}
__device__ __forceinline__ unsigned udmap(float x) {   // monotone float->uint map
    unsigned u = __float_as_uint(x);
    return ((int)u < 0) ? ~u : (u | 0x80000000u);
}

// ---------------- knn: ONE query per wave; compaction + radix top-16 (no serial insert) ----------------

__global__ void __launch_bounds__(256, 8) knn_kernel(const float* __restrict__ stile,
                                                     const int* __restrict__ tlo,
                                                     const int* __restrict__ thi,
                                                     int* __restrict__ knn) {
    __shared__ unsigned sbuf[4][128][2];   // [wave][slot][{ud, idx}] = 4KB
    const int lane = threadIdx.x & 63;
    const int wv   = threadIdx.x >> 6;
    const int s    = blockIdx.x * 4 + wv;   // sorted slot = this wave's query
    const int tq   = s >> 8;
    const int sl   = (s & 255) >> 2;        // self lane
    const int slot = s & 3;                 // self slot within lane

    const float* qp = stile + tq*1280 + (s & 255);
    const float qx = qp[0], qy = qp[256], qz = qp[512], qw = qp[768];
    const int   qi = reinterpret_cast<const int*>(qp)[1024];
    const f32x2 qx2 = {qx,qx}, qy2 = {qy,qy}, qz2 = {qz,qz}, qw2 = {qw,qw};

    const float* lbase = stile + lane*4;
    const bool is_self_lane = (lane == sl);

    // ---- pass 1: lane minima over the 5-tile x-window (disjoint candidate sets) ----
    float mn = INFF;
    int lo = tq - 2; if (lo < 0) lo = 0; if (lo > 27) lo = 27;
    #pragma unroll
    for (int tt = 0; tt < 5; ++tt) {
        const int t = lo + tt;
        const float* tp = lbase + t*1280;
        float4 X = *(const float4*)(tp);
        float4 Y = *(const float4*)(tp + 256);
        float4 Z = *(const float4*)(tp + 512);
        float4 S = *(const float4*)(tp + 768);
        f32x2 x01 = {X.x,X.y}, x23 = {X.z,X.w};
        f32x2 y01 = {Y.x,Y.y}, y23 = {Y.z,Y.w};
        f32x2 z01 = {Z.x,Z.y}, z23 = {Z.z,Z.w};
        f32x2 s01 = {S.x,S.y}, s23 = {S.z,S.w};
        f32x2 d01, d23;
        dist4(qx2, qy2, qz2, qw2, x01, x23, y01, y23, z01, z23, s01, s23, d01, d23);
        if ((t == tq) && is_self_lane) {
            if      (slot == 0) d01[0] = INFF;
            else if (slot == 1) d01[1] = INFF;
            else if (slot == 2) d23[0] = INFF;
            else                d23[1] = INFF;
        }
        mn = fminf(mn, fminf(fminf(d01[0], d01[1]), fminf(d23[0], d23[1])));
    }

    // ---- T = exact 16th smallest of the 64 lane minima (radix-select) ----
    float T;
    {
        unsigned ub = udmap(mn);
        unsigned long long alive = ~0ull;
        int need = KNN;
        #pragma unroll
        for (int b = 31; b >= 0; --b) {
            unsigned long long ones  = __ballot(((ub >> b) & 1u) != 0u);
            unsigned long long zeros = alive & ~ones;
            int cz = (int)__popcll(zeros);
            bool tz = (cz >= need);
            alive = tz ? zeros : (alive & ones);
            need  = tz ? need : (need - cz);
        }
        T = fmaxf(rdlane_f(mn, (int)__ffsll(alive) - 1), 0.f);  // clamp: skip-bound safety
    }

    // ---- visit mask in registers (one coalesced tlo/thi read) ----
    unsigned mask;
    {
        const int ti = lane & 31;
        const int bl = tlo[ti], bh = thi[ti];
        const float xlo = (bl == 0)   ? -1e30f : (bl * 0.03125f - 4.0f);
        const float xhi = (bh == 255) ?  1e30f : ((bh + 1) * 0.03125f - 4.0f);
        float gap = fmaxf(0.f, fmaxf(xlo - qx, qx - xhi));
        bool gate = (gap * gap <= T + 1e-3f);   // margin >> all fp32 rounding
        mask = (unsigned)__ballot(gate && (lane < 32));
    }

    // ---- pass 2: compact all candidates with d <= T into LDS (ballot-prefix, no chains) ----
    int cnt = 0;
    const unsigned long long ltm = (1ull << lane) - 1;

    auto push = [&](float dv, int idx) {
        bool pred = (dv <= T);                        // self is INF -> excluded
        unsigned long long bal = __ballot(pred);
        if (bal) {
            int posn = cnt + (int)__popcll(bal & ltm);
            if (pred && posn < 128) {
                sbuf[wv][posn][0] = udmap(dv);
                sbuf[wv][posn][1] = (unsigned)idx;
            }
            cnt += (int)__popcll(bal);
        }
    };

    while (mask) {
        const int t = (int)__ffs(mask) - 1;
        mask &= mask - 1;
        const float* tp = lbase + t*1280;
        float4 X = *(const float4*)(tp);
        float4 Y = *(const float4*)(tp + 256);
        float4 Z = *(const float4*)(tp + 512);
        float4 S = *(const float4*)(tp + 768);
        int4   I = *(const int4*)(tp + 1024);
        f32x2 x01 = {X.x,X.y}, x23 = {X.z,X.w};
        f32x2 y01 = {Y.x,Y.y}, y23 = {Y.z,Y.w};
        f32x2 z01 = {Z.x,Z.y}, z23 = {Z.z,Z.w};
        f32x2 s01 = {S.x,S.y}, s23 = {S.z,S.w};
        f32x2 d01, d23;
        dist4(qx2, qy2, qz2, qw2, x01, x23, y01, y23, z01, z23, s01, s23, d01, d23);
        if ((t == tq) && is_self_lane) {
            if      (slot == 0) d01[0] = INFF;
            else if (slot == 1) d01[1] = INFF;
            else if (slot == 2) d23[0] = INFF;
            else                d23[1] = INFF;
        }
        float tmin = fminf(fminf(d01[0], d01[1]), fminf(d23[0], d23[1]));
        if (__ballot(tmin <= T)) {
            push(d01[0], I.x);
            push(d01[1], I.y);
            push(d23[0], I.z);
            push(d23[1], I.w);
        }
    }

    // ---- exact top-16 of the compacted set: radix over ud, idx tie-break ----
    asm volatile("s_waitcnt lgkmcnt(0)" ::: "memory");
    const int M = (cnt > 128) ? 128 : cnt;   // M >= 16 guaranteed (16 lane minima <= T)
    unsigned ud1 = 0xFFFFFFFFu, id1 = 0xFFFFFFFFu;
    unsigned ud2 = 0xFFFFFFFFu, id2 = 0xFFFFFFFFu;
    if (lane < M)      { ud1 = sbuf[wv][lane][0];      id1 = sbuf[wv][lane][1]; }
    if (lane + 64 < M) { ud2 = sbuf[wv][lane + 64][0]; id2 = sbuf[wv][lane + 64][1]; }

    unsigned long long alive1 = __ballot(lane < M);
    unsigned long long alive2 = __ballot(lane + 64 < M);
    int need = KNN;
    #pragma unroll
    for (int b = 31; b >= 0; --b) {
        unsigned long long on1 = __ballot(((ud1 >> b) & 1u) != 0u);
        unsigned long long on2 = __ballot(((ud2 >> b) & 1u) != 0u);
        unsigned long long z1 = alive1 & ~on1;
        unsigned long long z2 = alive2 & ~on2;
        int cz = (int)__popcll(z1) + (int)__popcll(z2);
        bool tz = (cz >= need);
        alive1 = tz ? z1 : (alive1 & on1);
        alive2 = tz ? z2 : (alive2 & on2);
        need   = tz ? need : (need - cz);
    }
    unsigned v16;
    if (alive1) v16 = (unsigned)__builtin_amdgcn_readlane((int)ud1, (int)__ffsll(alive1) - 1);
    else        v16 = (unsigned)__builtin_amdgcn_readlane((int)ud2, (int)__ffsll(alive2) - 1);

    const int nt = (int)__popcll(alive1) + (int)__popcll(alive2);
    const bool all_ties = (nt <= need);
    unsigned vidx = 0xFFFFFFFFu;
    if (!all_ties) {   // duplicate d values: take `need` smallest idx among ties (rare)
        unsigned long long a1 = alive1, a2 = alive2;
        int nd = need;
        for (int b = 31; b >= 0; --b) {
            unsigned long long on1 = __ballot(((id1 >> b) & 1u) != 0u);
            unsigned long long on2 = __ballot(((id2 >> b) & 1u) != 0u);
            unsigned long long z1 = a1 & ~on1;
            unsigned long long z2 = a2 & ~on2;
            int cz = (int)__popcll(z1) + (int)__popcll(z2);
            bool tz = (cz >= nd);
            a1 = tz ? z1 : (a1 & on1);
            a2 = tz ? z2 : (a2 & on2);
            nd = tz ? nd : (nd - cz);
        }
        if (a1) vidx = (unsigned)__builtin_amdgcn_readlane((int)id1, (int)__ffsll(a1) - 1);
        else    vidx = (unsigned)__builtin_amdgcn_readlane((int)id2, (int)__ffsll(a2) - 1);
    }

    bool sel1 = (lane < M)      && ((ud1 < v16) || ((ud1 == v16) && (all_ties || (id1 <= vidx))));
    bool sel2 = (lane + 64 < M) && ((ud2 < v16) || ((ud2 == v16) && (all_ties || (id2 <= vidx))));
    unsigned long long bs1 = __ballot(sel1);
    if (sel1) knn[qi*KNN + (int)__popcll(bs1 & ltm)] = (int)id1;
    const int c1 = (int)__popcll(bs1);
    unsigned long long bs2 = __ballot(sel2);
    if (sel2) knn[qi*KNN + c1 + (int)__popcll(bs2 & ltm)] = (int)id2;
}

// ---------------- GEMM: Ub/Vb[N][384] = Xb @ Wpt^T (+ b1 on U), bf16 out ----------------
// 1 wave per block, 64 rows x 64 cols; C/D: col = lane&15, row = (lane>>4)*4 + q

__global__ void __launch_bounds__(64) gemm_kernel(const __hip_bfloat16* __restrict__ Xb,
                                                  const __hip_bfloat16* __restrict__ Wpt,
                                                  const float* __restrict__ b1,
                                                  __hip_bfloat16* __restrict__ Ub,
                                                  __hip_bfloat16* __restrict__ Vb) {
    const int lane = threadIdx.x;
    const int i0   = blockIdx.x * 64;
    const int f0   = blockIdx.y * 64;
    const int lm   = lane & 15;
    const int lk   = (lane >> 4) * 8;

    f32x4 acc[4][4];
    #pragma unroll
    for (int r = 0; r < 4; ++r)
        #pragma unroll
        for (int c = 0; c < 4; ++c)
            acc[r][c] = (f32x4){0.f, 0.f, 0.f, 0.f};

    const __hip_bfloat16* xbase = Xb  + (size_t)(i0 + lm) * KP + lk;
    const __hip_bfloat16* wbase = Wpt + (size_t)(f0 + lm) * KP + lk;

    #pragma unroll
    for (int kk = 0; kk < 13; ++kk) {
        short8 a[4], b[4];
        #pragma unroll
        for (int r = 0; r < 4; ++r)
            a[r] = *reinterpret_cast<const short8*>(xbase + (size_t)r*16*KP + kk*32);
        #pragma unroll
        for (int c = 0; c < 4; ++c)
            b[c] = *reinterpret_cast<const short8*>(wbase + (size_t)c*16*KP + kk*32);
        #pragma unroll
        for (int r = 0; r < 4; ++r)
            #pragma unroll
            for (int c = 0; c < 4; ++c)
                acc[r][c] = __builtin_amdgcn_mfma_f32_16x16x32_bf16(a[r], b[c], acc[r][c], 0, 0, 0);
    }

    const bool isU = (f0 < TD);
    __hip_bfloat16* outb = isU ? (Ub + f0) : (Vb + (f0 - TD));
    float bias[4] = {0.f, 0.f, 0.f, 0.f};
    if (isU) {
        #pragma unroll
        for (int c = 0; c < 4; ++c) bias[c] = b1[f0 + c*16 + lm];
    }
    const int crow = (lane >> 4) * 4;
    #pragma unroll
    for (int r = 0; r < 4; ++r)
        #pragma unroll
        for (int c = 0; c < 4; ++c)
            #pragma unroll
            for (int q = 0; q < 4; ++q)
                outb[(size_t)(i0 + r*16 + crow + q) * TD + c*16 + lm] =
                    __float2bfloat16(acc[r][c][q] + bias[c]);
}

// ---------------- final: dim-parallel (lane owns 6 dims), coalesced row reads ----------------
// Validated round 11: depth-2 batch pipeline, buffered partials, pipelined DPP reduce.

__device__ __forceinline__ float bflo(unsigned w) { return __uint_as_float(w << 16); }
__device__ __forceinline__ float bfhi(unsigned w) { return __uint_as_float(w & 0xFFFF0000u); }

template<int CTRL>
__device__ __forceinline__ float dppf(float v) {
    return __uint_as_float((unsigned)__builtin_amdgcn_update_dpp(
        0, (int)__float_as_uint(v), CTRL, 0xF, 0xF, true));
}

__global__ void __launch_bounds__(256) final_kernel(const __hip_bfloat16* __restrict__ Ub,
                                                    const __hip_bfloat16* __restrict__ Vb,
                                                    const int* __restrict__ knn,
                                                    const float* __restrict__ xyz,
                                                    const float* __restrict__ W2,
                                                    const float* __restrict__ b2,
                                                    float* __restrict__ out) {
    const int lane = threadIdx.x & 63;
    const int wv   = threadIdx.x >> 6;
    const int i    = blockIdx.x * 4 + wv;
    const int d0   = lane * 6;

    int jreg = knn[i*KNN + (lane & 15)];

    float u[6], w2l[6][3];
    {
        const unsigned* rowU = reinterpret_cast<const unsigned*>(Ub + (size_t)i * TD) + lane*3;
        unsigned a0 = rowU[0], a1 = rowU[1], a2 = rowU[2];
        u[0] = bflo(a0); u[1] = bfhi(a0);
        u[2] = bflo(a1); u[3] = bfhi(a1);
        u[4] = bflo(a2); u[5] = bfhi(a2);
    }
    #pragma unroll
    for (int t = 0; t < 6; ++t)
        #pragma unroll
        for (int c = 0; c < 3; ++c) w2l[t][c] = W2[(d0 + t)*3 + c];

    const unsigned* vbase = reinterpret_cast<const unsigned*>(Vb);
    const int voff = lane * 3;

    float pk0[16], pk1[16], pk2[16];
    unsigned va[2][4][3];

    #pragma unroll
    for (int t = 0; t < 4; ++t) {
        int j = __builtin_amdgcn_readlane(jreg, t);
        const unsigned* rv = vbase + (size_t)j * 192 + voff;
        va[0][t][0] = rv[0]; va[0][t][1] = rv[1]; va[0][t][2] = rv[2];
    }
    __builtin_amdgcn_sched_barrier(0);

    #pragma unroll
    for (int b = 0; b < 4; ++b) {
        if (b < 3) {
            #pragma unroll
            for (int t = 0; t < 4; ++t) {
                int j = __builtin_amdgcn_readlane(jreg, (b+1)*4 + t);
                const unsigned* rv = vbase + (size_t)j * 192 + voff;
                va[(b+1)&1][t][0] = rv[0];
                va[(b+1)&1][t][1] = rv[1];
                va[(b+1)&1][t][2] = rv[2];
            }
            __builtin_amdgcn_sched_barrier(0);
        }
        #pragma unroll
        for (int t = 0; t < 4; ++t) {
            const int kk = b*4 + t;
            unsigned a0 = va[b&1][t][0], a1 = va[b&1][t][1], a2 = va[b&1][t][2];
            float v0 = bflo(a0), v1 = bfhi(a0);
            float v2 = bflo(a1), v3 = bfhi(a1);
            float v4 = bflo(a2), v5 = bfhi(a2);
            float h0 = fmaxf(u[0] + v0, 0.f), h1 = fmaxf(u[1] + v1, 0.f);
            float h2 = fmaxf(u[2] + v2, 0.f), h3 = fmaxf(u[3] + v3, 0.f);
            float h4 = fmaxf(u[4] + v4, 0.f), h5 = fmaxf(u[5] + v5, 0.f);
            float s0 = 0.f, s1 = 0.f, s2 = 0.f;
            s0 = fmaf(h0, w2l[0][0], s0); s1 = fmaf(h0, w2l[0][1], s1); s2 = fmaf(h0, w2l[0][2], s2);
            s0 = fmaf(h1, w2l[1][0], s0); s1 = fmaf(h1, w2l[1][1], s1); s2 = fmaf(h1, w2l[1][2], s2);
            s0 = fmaf(h2, w2l[2][0], s0); s1 = fmaf(h2, w2l[2][1], s1); s2 = fmaf(h2, w2l[2][2], s2);
            s0 = fmaf(h3, w2l[3][0], s0); s1 = fmaf(h3, w2l[3][1], s1); s2 = fmaf(h3, w2l[3][2], s2);
            s0 = fmaf(h4, w2l[4][0], s0); s1 = fmaf(h4, w2l[4][1], s1); s2 = fmaf(h4, w2l[4][2], s2);
            s0 = fmaf(h5, w2l[5][0], s0); s1 = fmaf(h5, w2l[5][1], s1); s2 = fmaf(h5, w2l[5][2], s2);
            pk0[kk] = s0; pk1[kk] = s1; pk2[kk] = s2;
        }
    }

    #pragma unroll
    for (int kk = 0; kk < 16; ++kk) {
        float r0 = pk0[kk], r1 = pk1[kk], r2 = pk2[kk];
        r0 += dppf<0x121>(r0); r1 += dppf<0x121>(r1); r2 += dppf<0x121>(r2);
        r0 += dppf<0x122>(r0); r1 += dppf<0x122>(r1); r2 += dppf<0x122>(r2);
        r0 += dppf<0x124>(r0); r1 += dppf<0x124>(r1); r2 += dppf<0x124>(r2);
        r0 += dppf<0x128>(r0); r1 += dppf<0x128>(r1); r2 += dppf<0x128>(r2);
        r0 += __shfl_xor(r0, 16); r1 += __shfl_xor(r1, 16); r2 += __shfl_xor(r2, 16);
        r0 += __shfl_xor(r0, 32); r1 += __shfl_xor(r1, 32); r2 += __shfl_xor(r2, 32);
        pk0[kk] = r0; pk1[kk] = r1; pk2[kk] = r2;
    }
    float mx0 = pk0[0], mx1 = pk1[0], mx2 = pk2[0];
    #pragma unroll
    for (int kk = 1; kk < 16; ++kk) {
        mx0 = fmaxf(mx0, pk0[kk]);
        mx1 = fmaxf(mx1, pk1[kk]);
        mx2 = fmaxf(mx2, pk2[kk]);
    }

    if (lane == 0) {
        out[i*3+0] = xyz[i*3+0] + mx0 + b2[0];
        out[i*3+1] = xyz[i*3+1] + mx1 + b2[1];
        out[i*3+2] = xyz[i*3+2] + mx2 + b2[2];
    }
}

// ---------------- launch ----------------

extern "C" void kernel_launch(void* const* d_in, const int* in_sizes, int n_in,
                              void* d_out, int out_size, void* d_ws, size_t ws_size,
                              hipStream_t stream) {
    const float* xyz  = (const float*)d_in[0];
    const float* feat = (const float*)d_in[1];
    const float* W1   = (const float*)d_in[2];
    const float* b1   = (const float*)d_in[3];
    const float* W2   = (const float*)d_in[4];
    const float* b2   = (const float*)d_in[5];
    float* out = (float*)d_out;

    char* ws = (char*)d_ws;
    int*            knn   = (int*)(ws + 0);                   //   524288 B
    float*          stile = (float*)(ws + 524288);            //   163840 B
    __hip_bfloat16* Xb    = (__hip_bfloat16*)(ws + 688128);   //  6815744 B
    __hip_bfloat16* Wpt   = (__hip_bfloat16*)(ws + 7503872);  //   638976 B
    __hip_bfloat16* Ub    = (__hip_bfloat16*)(ws + 8142848);  //  6291456 B
    __hip_bfloat16* Vb    = (__hip_bfloat16*)(ws + 14434304); //  6291456 B
    int*            cut   = (int*)(ws + 20725760);            //     1024 B
    int*            thi   = (int*)(ws + 20726784);            //      128 B
    int*            tlo   = (int*)(ws + 20726912);            //      128 B -> end 20727040

    prep_all     <<<dim3(N + NF + 1),  dim3(128), 0, stream>>>(feat, xyz, W1, Xb, Wpt, cut);
    assign_kernel<<<dim3(N/256),       dim3(256), 0, stream>>>(xyz, cut, tlo, thi, stile);
    knn_kernel   <<<dim3(N/4),         dim3(256), 0, stream>>>(stile, tlo, thi, knn);
    gemm_kernel  <<<dim3(N/64, NF/64), dim3(64),  0, stream>>>(Xb, Wpt, b1, Ub, Vb);
    final_kernel <<<dim3(N/4),         dim3(256), 0, stream>>>(Ub, Vb, knn, xyz, W2, b2, out);
}

// Round 17
// 82.446 us; speedup vs baseline: 1.4828x; 1.0426x over previous
//
#include <hip/hip_runtime.h>
#include <hip/hip_bf16.h>

// GNNRefiner: out = xyz + max_k( relu([x_i, x_j-x_i]·W1 + b1)·W2 + b2 )
// Factorization: e·W1 = x_i·(A-B) + x_j·B  with A=W1[0:387], B=W1[387:774].
// Pipeline (5 dispatches): prep(+cut init block) -> assign(per-block full hist + scan
//           + bounds + scatter) -> knn (1 query/wave, LDS-cached 5-tile window:
//           pass-1 computes+caches distances, pass-2 reads cache + idx only,
//           ballot-prefix compaction + radix top-16) -> MFMA GEMM (+b1) -> final (r11).
// KNN: T = 16th-smallest of 64 disjoint-set lane minima (provable D16 upper bound);
// tile skipped iff gap^2 > T + 1e-3; selection = exact 16 smallest (d, idx) — set-
// identical to reference (downstream max over k is order-invariant).

#define N 8192
#define TD 384      // TOKEN_DIM
#define KNN 16
#define DX 387      // TD + 3
#define KP 416      // DX padded to multiple of 32
#define NF 768      // 2*TD output cols of fused GEMM
#define INFF __builtin_inff()

typedef __attribute__((ext_vector_type(8))) short short8;
typedef __attribute__((ext_vector_type(4))) float f32x4;
typedef __attribute__((ext_vector_type(2))) float f32x2;

// ---------------- packed fp32 helpers (bit-identical to scalar ops, 2 cands/instr) ----------------

__device__ __forceinline__ f32x2 pk_mul(f32x2 a, f32x2 b) {
    f32x2 r; asm("v_pk_mul_f32 %0, %1, %2" : "=v"(r) : "v"(a), "v"(b)); return r;
}
__device__ __forceinline__ f32x2 pk_add(f32x2 a, f32x2 b) {
    f32x2 r; asm("v_pk_add_f32 %0, %1, %2" : "=v"(r) : "v"(a), "v"(b)); return r;
}
__device__ __forceinline__ f32x2 pk_sub(f32x2 a, f32x2 b) {  // a - b, same rounding as fsub
    f32x2 r; asm("v_pk_add_f32 %0, %1, %2 neg_lo:[0,1] neg_hi:[0,1]" : "=v"(r) : "v"(a), "v"(b)); return r;
}
__device__ __forceinline__ f32x2 pk_fma(f32x2 a, f32x2 b, f32x2 c) {
    f32x2 r; asm("v_pk_fma_f32 %0, %1, %2, %3" : "=v"(r) : "v"(a), "v"(b), "v"(c)); return r;
}

// d2 = (qw + sq_j) - 2*dot, dot = fma(qz,z, fma(qy,y, mul(qx,x)))  [bit-identical to ref]
__device__ __forceinline__ void dist4(f32x2 qx, f32x2 qy, f32x2 qz, f32x2 qw,
                                      f32x2 x01, f32x2 x23, f32x2 y01, f32x2 y23,
                                      f32x2 z01, f32x2 z23, f32x2 s01, f32x2 s23,
                                      f32x2& d01, f32x2& d23) {
    f32x2 dot01 = pk_fma(qz, z01, pk_fma(qy, y01, pk_mul(qx, x01)));
    f32x2 dot23 = pk_fma(qz, z23, pk_fma(qy, y23, pk_mul(qx, x23)));
    d01 = pk_sub(pk_add(qw, s01), pk_add(dot01, dot01));  // dot+dot == 2*dot exactly
    d23 = pk_sub(pk_add(qw, s23), pk_add(dot23, dot23));
}

// x-sort bin (identical expression everywhere -> deterministic)
__device__ __forceinline__ int xbin(float x) {
    int b = (int)((x + 4.0f) * 32.0f);
    return b < 0 ? 0 : (b > 255 ? 255 : b);
}

// ---------------- prep: Xb rows + Wpt; LAST block zeroes the cut cursor ----------------

__global__ void __launch_bounds__(128) prep_all(const float* __restrict__ feat,
                                                const float* __restrict__ xyz,
                                                const float* __restrict__ W1,
                                                __hip_bfloat16* __restrict__ Xb,
                                                __hip_bfloat16* __restrict__ Wpt,
                                                int* __restrict__ cut) {
    int b = blockIdx.x;
    int t = threadIdx.x;
    if (b < N) {
        if (t < 96) {  // vectorized feat copy: 96 x float4 -> 4 x bf16
            float4 f = reinterpret_cast<const float4*>(feat + (size_t)b*TD)[t];
            __hip_bfloat16 h[4] = {__float2bfloat16(f.x), __float2bfloat16(f.y),
                                   __float2bfloat16(f.z), __float2bfloat16(f.w)};
            *reinterpret_cast<ulonglong1*>(Xb + b*KP + t*4) = *reinterpret_cast<ulonglong1*>(h);
        } else {       // tail d = TD..KP-1 spread across threads 96..127
            int d = TD + (t - 96);
            float v = (d < DX) ? xyz[b*3 + (d - TD)] : 0.f;
            Xb[b*KP + d] = __float2bfloat16(v);
        }
    } else if (b < N + NF) {
        int f = b - N;  // 0..767
        for (int k = t; k < KP; k += 128) {
            float v = 0.f;
            if (k < DX) {
                if (f < TD) v = W1[k*TD + f] - W1[(DX+k)*TD + f];
                else        v = W1[(DX+k)*TD + (f - TD)];
            }
            Wpt[f*KP + k] = __float2bfloat16(v);
        }
    } else {           // init block: zero the 256-entry cut cursor (runs before assign)
        cut[t] = 0;
        cut[t + 128] = 0;
    }
}

// ---------------- assign: 32 blocks; per-block full hist + scan + bounds + scatter ----------------
// sorted tiles: per 256-slot tile: [x(256)|y(256)|z(256)|sq(256)|idx(256)] (5120B)

__global__ void __launch_bounds__(256) assign_kernel(const float* __restrict__ xyz,
                                                     int* __restrict__ cut,
                                                     int* __restrict__ tlo,
                                                     int* __restrict__ thi,
                                                     float* __restrict__ stile) {
    __shared__ int hcnt[256];
    __shared__ int base[256];
    __shared__ int stlo[32], sthi[32];
    const int t = threadIdx.x;

    hcnt[t] = 0;
    if (t < 32) { stlo[t] = 255; sthi[t] = 0; }
    __syncthreads();

    // full histogram (all blocks compute identically; 8192 x-reads, L2-hot)
    #pragma unroll
    for (int c = 0; c < 32; ++c) {
        atomicAdd(&hcnt[xbin(xyz[(t + c*256)*3])], 1);
    }
    __syncthreads();

    const int v = hcnt[t];
    base[t] = v;
    __syncthreads();
    for (int off = 1; off < 256; off <<= 1) {
        int add = (t >= off) ? base[t - off] : 0;
        __syncthreads();
        base[t] += add;
        __syncthreads();
    }
    const int end = base[t], start = end - v;   // inclusive / exclusive prefix
    __syncthreads();
    base[t] = start;
    __syncthreads();

    if (blockIdx.x == 0) {   // per-tile conservative bin range, direct write
        if (v > 0) {
            for (int x = start >> 8; x <= (end - 1) >> 8; ++x) {
                atomicMin(&stlo[x], t);
                atomicMax(&sthi[x], t);
            }
        }
        __syncthreads();
        if (t < 32) { tlo[t] = stlo[t]; thi[t] = sthi[t]; }
    }

    // scatter this block's 256 points
    const int i = blockIdx.x * 256 + t;
    float x = xyz[i*3+0], y = xyz[i*3+1], z = xyz[i*3+2];
    int bin = xbin(x);
    int pos = base[bin] + atomicAdd(&cut[bin], 1);
    float sq = __fadd_rn(__fadd_rn(__fmul_rn(x,x), __fmul_rn(y,y)), __fmul_rn(z,z));
    float* tp = stile + (pos >> 8) * 1280 + (pos & 255);
    tp[0] = x; tp[256] = y; tp[512] = z; tp[768] = sq;
    reinterpret_cast<int*>(tp)[1024] = i;
}

// ---------------- knn helpers ----------------

__device__ __forceinline__ float rdlane_f(float v, int src) {
    return __uint_as_float(__builtin_amdgcn_readlane(__float_as_uint(v), src));
}
__device__ __forceinline__ unsigned udmap(float x) {   // monotone float->uint map
    unsigned u = __float_as_uint(x);
    return ((int)u < 0) ? ~u : (u | 0x80000000u);
}

// ---------------- knn: ONE query per wave; LDS-cached window; compaction + radix top-16 ----------------

__global__ void __launch_bounds__(256, 6) knn_kernel(const float* __restrict__ stile,
                                                     const int* __restrict__ tlo,
                                                     const int* __restrict__ thi,
                                                     int* __restrict__ knn) {
    __shared__ float    dcache[4][5][256];   // 20KB: pass-1 window distances (self = INF)
    __shared__ unsigned sbuf[4][128][2];     //  4KB: compacted (ud, idx)
    const int lane = threadIdx.x & 63;
    const int wv   = threadIdx.x >> 6;
    const int s    = blockIdx.x * 4 + wv;   // sorted slot = this wave's query
    const int tq   = s >> 8;
    const int sl   = (s & 255) >> 2;        // self lane
    const int slot = s & 3;                 // self slot within lane

    const float* qp = stile + tq*1280 + (s & 255);
    const float qx = qp[0], qy = qp[256], qz = qp[512], qw = qp[768];
    const int   qi = reinterpret_cast<const int*>(qp)[1024];
    const f32x2 qx2 = {qx,qx}, qy2 = {qy,qy}, qz2 = {qz,qz}, qw2 = {qw,qw};

    const float* lbase = stile + lane*4;
    const bool is_self_lane = (lane == sl);

    // ---- pass 1: compute + LDS-cache distances over the 5-tile x-window ----
    float mn = INFF;
    int lo = tq - 2; if (lo < 0) lo = 0; if (lo > 27) lo = 27;
    #pragma unroll
    for (int tt = 0; tt < 5; ++tt) {
        const int t = lo + tt;
        const float* tp = lbase + t*1280;
        float4 X = *(const float4*)(tp);
        float4 Y = *(const float4*)(tp + 256);
        float4 Z = *(const float4*)(tp + 512);
        float4 S = *(const float4*)(tp + 768);
        f32x2 x01 = {X.x,X.y}, x23 = {X.z,X.w};
        f32x2 y01 = {Y.x,Y.y}, y23 = {Y.z,Y.w};
        f32x2 z01 = {Z.x,Z.y}, z23 = {Z.z,Z.w};
        f32x2 s01 = {S.x,S.y}, s23 = {S.z,S.w};
        f32x2 d01, d23;
        dist4(qx2, qy2, qz2, qw2, x01, x23, y01, y23, z01, z23, s01, s23, d01, d23);
        if ((t == tq) && is_self_lane) {
            if      (slot == 0) d01[0] = INFF;
            else if (slot == 1) d01[1] = INFF;
            else if (slot == 2) d23[0] = INFF;
            else                d23[1] = INFF;
        }
        f32x4 dd = {d01[0], d01[1], d23[0], d23[1]};
        *reinterpret_cast<f32x4*>(&dcache[wv][tt][lane*4]) = dd;
        mn = fminf(mn, fminf(fminf(dd[0], dd[1]), fminf(dd[2], dd[3])));
    }

    // ---- T = exact 16th smallest of the 64 lane minima (radix-select) ----
    float T;
    {
        unsigned ub = udmap(mn);
        unsigned long long alive = ~0ull;
        int need = KNN;
        #pragma unroll
        for (int b = 31; b >= 0; --b) {
            unsigned long long ones  = __ballot(((ub >> b) & 1u) != 0u);
            unsigned long long zeros = alive & ~ones;
            int cz = (int)__popcll(zeros);
            bool tz = (cz >= need);
            alive = tz ? zeros : (alive & ones);
            need  = tz ? need : (need - cz);
        }
        T = fmaxf(rdlane_f(mn, (int)__ffsll(alive) - 1), 0.f);  // clamp: skip-bound safety
    }

    // ---- visit mask in registers (one coalesced tlo/thi read) ----
    unsigned mask;
    {
        const int ti = lane & 31;
        const int bl = tlo[ti], bh = thi[ti];
        const float xlo = (bl == 0)   ? -1e30f : (bl * 0.03125f - 4.0f);
        const float xhi = (bh == 255) ?  1e30f : ((bh + 1) * 0.03125f - 4.0f);
        float gap = fmaxf(0.f, fmaxf(xlo - qx, qx - xhi));
        bool gate = (gap * gap <= T + 1e-3f);   // margin >> all fp32 rounding
        mask = (unsigned)__ballot(gate && (lane < 32));
    }

    // ---- pass 2: compact candidates with d <= T (ballot-prefix, no serial chains) ----
    int cnt = 0;
    const unsigned long long ltm = (1ull << lane) - 1;

    auto push = [&](float dv, int idx) {
        bool pred = (dv <= T);                        // self is INF -> excluded
        unsigned long long bal = __ballot(pred);
        if (bal) {
            int posn = cnt + (int)__popcll(bal & ltm);
            if (pred && posn < 128) {
                sbuf[wv][posn][0] = udmap(dv);
                sbuf[wv][posn][1] = (unsigned)idx;
            }
            cnt += (int)__popcll(bal);
        }
    };

    // 2a: window tiles — read cached distances + idx vector only
    #pragma unroll
    for (int tt = 0; tt < 5; ++tt) {
        const int t = lo + tt;
        if (!((mask >> t) & 1u)) continue;            // wave-uniform
        f32x4 dd = *reinterpret_cast<const f32x4*>(&dcache[wv][tt][lane*4]);
        int4 I = *(const int4*)(lbase + t*1280 + 1024);
        push(dd[0], I.x);
        push(dd[1], I.y);
        push(dd[2], I.z);
        push(dd[3], I.w);
    }
    // 2b: rare out-of-window survivors — recompute (t != tq, no self check needed)
    unsigned rest = mask & ~(0x1Fu << lo);
    while (rest) {
        const int t = (int)__ffs(rest) - 1;
        rest &= rest - 1;
        const float* tp = lbase + t*1280;
        float4 X = *(const float4*)(tp);
        float4 Y = *(const float4*)(tp + 256);
        float4 Z = *(const float4*)(tp + 512);
        float4 S = *(const float4*)(tp + 768);
        int4   I = *(const int4*)(tp + 1024);
        f32x2 x01 = {X.x,X.y}, x23 = {X.z,X.w};
        f32x2 y01 = {Y.x,Y.y}, y23 = {Y.z,Y.w};
        f32x2 z01 = {Z.x,Z.y}, z23 = {Z.z,Z.w};
        f32x2 s01 = {S.x,S.y}, s23 = {S.z,S.w};
        f32x2 d01, d23;
        dist4(qx2, qy2, qz2, qw2, x01, x23, y01, y23, z01, z23, s01, s23, d01, d23);
        float tmin = fminf(fminf(d01[0], d01[1]), fminf(d23[0], d23[1]));
        if (__ballot(tmin <= T)) {
            push(d01[0], I.x);
            push(d01[1], I.y);
            push(d23[0], I.z);
            push(d23[1], I.w);
        }
    }

    // ---- exact top-16 of the compacted set: radix over ud, idx tie-break ----
    asm volatile("s_waitcnt lgkmcnt(0)" ::: "memory");
    const int M = (cnt > 128) ? 128 : cnt;   // M >= 16 guaranteed (16 lane minima <= T)

    if (M <= 64) {   // fast path (typical: M ~ 20-40)
        unsigned ud1 = 0xFFFFFFFFu, id1 = 0xFFFFFFFFu;
        if (lane < M) { ud1 = sbuf[wv][lane][0]; id1 = sbuf[wv][lane][1]; }
        unsigned long long alive = __ballot(lane < M);
        int need = KNN;
        #pragma unroll
        for (int b = 31; b >= 0; --b) {
            unsigned long long on = __ballot(((ud1 >> b) & 1u) != 0u);
            unsigned long long z  = alive & ~on;
            int cz = (int)__popcll(z);
            bool tz = (cz >= need);
            alive = tz ? z : (alive & on);
            need  = tz ? need : (need - cz);
        }
        unsigned v16 = (unsigned)__builtin_amdgcn_readlane((int)ud1, (int)__ffsll(alive) - 1);
        const bool all_ties = ((int)__popcll(alive) <= need);
        unsigned vidx = 0xFFFFFFFFu;
        if (!all_ties) {   // duplicate d: take `need` smallest idx among ties (rare)
            unsigned long long a = alive;
            int nd = need;
            for (int b = 31; b >= 0; --b) {
                unsigned long long on = __ballot(((id1 >> b) & 1u) != 0u);
                unsigned long long z  = a & ~on;
                int cz = (int)__popcll(z);
                bool tz = (cz >= nd);
                a  = tz ? z : (a & on);
                nd = tz ? nd : (nd - cz);
            }
            vidx = (unsigned)__builtin_amdgcn_readlane((int)id1, (int)__ffsll(a) - 1);
        }
        bool sel = (lane < M) && ((ud1 < v16) || ((ud1 == v16) && (all_ties || (id1 <= vidx))));
        unsigned long long bs = __ballot(sel);
        if (sel) knn[qi*KNN + (int)__popcll(bs & ltm)] = (int)id1;
    } else {
        unsigned ud1 = 0xFFFFFFFFu, id1 = 0xFFFFFFFFu;
        unsigned ud2 = 0xFFFFFFFFu, id2 = 0xFFFFFFFFu;
        if (lane < M)      { ud1 = sbuf[wv][lane][0];      id1 = sbuf[wv][lane][1]; }
        if (lane + 64 < M) { ud2 = sbuf[wv][lane + 64][0]; id2 = sbuf[wv][lane + 64][1]; }

        unsigned long long alive1 = __ballot(lane < M);
        unsigned long long alive2 = __ballot(lane + 64 < M);
        int need = KNN;
        #pragma unroll
        for (int b = 31; b >= 0; --b) {
            unsigned long long on1 = __ballot(((ud1 >> b) & 1u) != 0u);
            unsigned long long on2 = __ballot(((ud2 >> b) & 1u) != 0u);
            unsigned long long z1 = alive1 & ~on1;
            unsigned long long z2 = alive2 & ~on2;
            int cz = (int)__popcll(z1) + (int)__popcll(z2);
            bool tz = (cz >= need);
            alive1 = tz ? z1 : (alive1 & on1);
            alive2 = tz ? z2 : (alive2 & on2);
            need   = tz ? need : (need - cz);
        }
        unsigned v16;
        if (alive1) v16 = (unsigned)__builtin_amdgcn_readlane((int)ud1, (int)__ffsll(alive1) - 1);
        else        v16 = (unsigned)__builtin_amdgcn_readlane((int)ud2, (int)__ffsll(alive2) - 1);

        const int nt = (int)__popcll(alive1) + (int)__popcll(alive2);
        const bool all_ties = (nt <= need);
        unsigned vidx = 0xFFFFFFFFu;
        if (!all_ties) {
            unsigned long long a1 = alive1, a2 = alive2;
            int nd = need;
            for (int b = 31; b >= 0; --b) {
                unsigned long long on1 = __ballot(((id1 >> b) & 1u) != 0u);
                unsigned long long on2 = __ballot(((id2 >> b) & 1u) != 0u);
                unsigned long long z1 = a1 & ~on1;
                unsigned long long z2 = a2 & ~on2;
                int cz = (int)__popcll(z1) + (int)__popcll(z2);
                bool tz = (cz >= nd);
                a1 = tz ? z1 : (a1 & on1);
                a2 = tz ? z2 : (a2 & on2);
                nd = tz ? nd : (nd - cz);
            }
            if (a1) vidx = (unsigned)__builtin_amdgcn_readlane((int)id1, (int)__ffsll(a1) - 1);
            else    vidx = (unsigned)__builtin_amdgcn_readlane((int)id2, (int)__ffsll(a2) - 1);
        }

        bool sel1 = (lane < M)      && ((ud1 < v16) || ((ud1 == v16) && (all_ties || (id1 <= vidx))));
        bool sel2 = (lane + 64 < M) && ((ud2 < v16) || ((ud2 == v16) && (all_ties || (id2 <= vidx))));
        unsigned long long bs1 = __ballot(sel1);
        if (sel1) knn[qi*KNN + (int)__popcll(bs1 & ltm)] = (int)id1;
        const int c1 = (int)__popcll(bs1);
        unsigned long long bs2 = __ballot(sel2);
        if (sel2) knn[qi*KNN + c1 + (int)__popcll(bs2 & ltm)] = (int)id2;
    }
}

// ---------------- GEMM: Ub/Vb[N][384] = Xb @ Wpt^T (+ b1 on U), bf16 out ----------------
// 1 wave per block, 64 rows x 64 cols; C/D: col = lane&15, row = (lane>>4)*4 + q

__global__ void __launch_bounds__(64) gemm_kernel(const __hip_bfloat16* __restrict__ Xb,
                                                  const __hip_bfloat16* __restrict__ Wpt,
                                                  const float* __restrict__ b1,
                                                  __hip_bfloat16* __restrict__ Ub,
                                                  __hip_bfloat16* __restrict__ Vb) {
    const int lane = threadIdx.x;
    const int i0   = blockIdx.x * 64;
    const int f0   = blockIdx.y * 64;
    const int lm   = lane & 15;
    const int lk   = (lane >> 4) * 8;

    f32x4 acc[4][4];
    #pragma unroll
    for (int r = 0; r < 4; ++r)
        #pragma unroll
        for (int c = 0; c < 4; ++c)
            acc[r][c] = (f32x4){0.f, 0.f, 0.f, 0.f};

    const __hip_bfloat16* xbase = Xb  + (size_t)(i0 + lm) * KP + lk;
    const __hip_bfloat16* wbase = Wpt + (size_t)(f0 + lm) * KP + lk;

    #pragma unroll
    for (int kk = 0; kk < 13; ++kk) {
        short8 a[4], b[4];
        #pragma unroll
        for (int r = 0; r < 4; ++r)
            a[r] = *reinterpret_cast<const short8*>(xbase + (size_t)r*16*KP + kk*32);
        #pragma unroll
        for (int c = 0; c < 4; ++c)
            b[c] = *reinterpret_cast<const short8*>(wbase + (size_t)c*16*KP + kk*32);
        #pragma unroll
        for (int r = 0; r < 4; ++r)
            #pragma unroll
            for (int c = 0; c < 4; ++c)
                acc[r][c] = __builtin_amdgcn_mfma_f32_16x16x32_bf16(a[r], b[c], acc[r][c], 0, 0, 0);
    }

    const bool isU = (f0 < TD);
    __hip_bfloat16* outb = isU ? (Ub + f0) : (Vb + (f0 - TD));
    float bias[4] = {0.f, 0.f, 0.f, 0.f};
    if (isU) {
        #pragma unroll
        for (int c = 0; c < 4; ++c) bias[c] = b1[f0 + c*16 + lm];
    }
    const int crow = (lane >> 4) * 4;
    #pragma unroll
    for (int r = 0; r < 4; ++r)
        #pragma unroll
        for (int c = 0; c < 4; ++c)
            #pragma unroll
            for (int q = 0; q < 4; ++q)
                outb[(size_t)(i0 + r*16 + crow + q) * TD + c*16 + lm] =
                    __float2bfloat16(acc[r][c][q] + bias[c]);
}

// ---------------- final: dim-parallel (lane owns 6 dims), coalesced row reads ----------------
// Validated round 11: depth-2 batch pipeline, buffered partials, pipelined DPP reduce.

__device__ __forceinline__ float bflo(unsigned w) { return __uint_as_float(w << 16); }
__device__ __forceinline__ float bfhi(unsigned w) { return __uint_as_float(w & 0xFFFF0000u); }

template<int CTRL>
__device__ __forceinline__ float dppf(float v) {
    return __uint_as_float((unsigned)__builtin_amdgcn_update_dpp(
        0, (int)__float_as_uint(v), CTRL, 0xF, 0xF, true));
}

__global__ void __launch_bounds__(256) final_kernel(const __hip_bfloat16* __restrict__ Ub,
                                                    const __hip_bfloat16* __restrict__ Vb,
                                                    const int* __restrict__ knn,
                                                    const float* __restrict__ xyz,
                                                    const float* __restrict__ W2,
                                                    const float* __restrict__ b2,
                                                    float* __restrict__ out) {
    const int lane = threadIdx.x & 63;
    const int wv   = threadIdx.x >> 6;
    const int i    = blockIdx.x * 4 + wv;
    const int d0   = lane * 6;

    int jreg = knn[i*KNN + (lane & 15)];

    float u[6], w2l[6][3];
    {
        const unsigned* rowU = reinterpret_cast<const unsigned*>(Ub + (size_t)i * TD) + lane*3;
        unsigned a0 = rowU[0], a1 = rowU[1], a2 = rowU[2];
        u[0] = bflo(a0); u[1] = bfhi(a0);
        u[2] = bflo(a1); u[3] = bfhi(a1);
        u[4] = bflo(a2); u[5] = bfhi(a2);
    }
    #pragma unroll
    for (int t = 0; t < 6; ++t)
        #pragma unroll
        for (int c = 0; c < 3; ++c) w2l[t][c] = W2[(d0 + t)*3 + c];

    const unsigned* vbase = reinterpret_cast<const unsigned*>(Vb);
    const int voff = lane * 3;

    float pk0[16], pk1[16], pk2[16];
    unsigned va[2][4][3];

    #pragma unroll
    for (int t = 0; t < 4; ++t) {
        int j = __builtin_amdgcn_readlane(jreg, t);
        const unsigned* rv = vbase + (size_t)j * 192 + voff;
        va[0][t][0] = rv[0]; va[0][t][1] = rv[1]; va[0][t][2] = rv[2];
    }
    __builtin_amdgcn_sched_barrier(0);

    #pragma unroll
    for (int b = 0; b < 4; ++b) {
        if (b < 3) {
            #pragma unroll
            for (int t = 0; t < 4; ++t) {
                int j = __builtin_amdgcn_readlane(jreg, (b+1)*4 + t);
                const unsigned* rv = vbase + (size_t)j * 192 + voff;
                va[(b+1)&1][t][0] = rv[0];
                va[(b+1)&1][t][1] = rv[1];
                va[(b+1)&1][t][2] = rv[2];
            }
            __builtin_amdgcn_sched_barrier(0);
        }
        #pragma unroll
        for (int t = 0; t < 4; ++t) {
            const int kk = b*4 + t;
            unsigned a0 = va[b&1][t][0], a1 = va[b&1][t][1], a2 = va[b&1][t][2];
            float v0 = bflo(a0), v1 = bfhi(a0);
            float v2 = bflo(a1), v3 = bfhi(a1);
            float v4 = bflo(a2), v5 = bfhi(a2);
            float h0 = fmaxf(u[0] + v0, 0.f), h1 = fmaxf(u[1] + v1, 0.f);
            float h2 = fmaxf(u[2] + v2, 0.f), h3 = fmaxf(u[3] + v3, 0.f);
            float h4 = fmaxf(u[4] + v4, 0.f), h5 = fmaxf(u[5] + v5, 0.f);
            float s0 = 0.f, s1 = 0.f, s2 = 0.f;
            s0 = fmaf(h0, w2l[0][0], s0); s1 = fmaf(h0, w2l[0][1], s1); s2 = fmaf(h0, w2l[0][2], s2);
            s0 = fmaf(h1, w2l[1][0], s0); s1 = fmaf(h1, w2l[1][1], s1); s2 = fmaf(h1, w2l[1][2], s2);
            s0 = fmaf(h2, w2l[2][0], s0); s1 = fmaf(h2, w2l[2][1], s1); s2 = fmaf(h2, w2l[2][2], s2);
            s0 = fmaf(h3, w2l[3][0], s0); s1 = fmaf(h3, w2l[3][1], s1); s2 = fmaf(h3, w2l[3][2], s2);
            s0 = fmaf(h4, w2l[4][0], s0); s1 = fmaf(h4, w2l[4][1], s1); s2 = fmaf(h4, w2l[4][2], s2);
            s0 = fmaf(h5, w2l[5][0], s0); s1 = fmaf(h5, w2l[5][1], s1); s2 = fmaf(h5, w2l[5][2], s2);
            pk0[kk] = s0; pk1[kk] = s1; pk2[kk] = s2;
        }
    }

    #pragma unroll
    for (int kk = 0; kk < 16; ++kk) {
        float r0 = pk0[kk], r1 = pk1[kk], r2 = pk2[kk];
        r0 += dppf<0x121>(r0); r1 += dppf<0x121>(r1); r2 += dppf<0x121>(r2);
        r0 += dppf<0x122>(r0); r1 += dppf<0x122>(r1); r2 += dppf<0x122>(r2);
        r0 += dppf<0x124>(r0); r1 += dppf<0x124>(r1); r2 += dppf<0x124>(r2);
        r0 += dppf<0x128>(r0); r1 += dppf<0x128>(r1); r2 += dppf<0x128>(r2);
        r0 += __shfl_xor(r0, 16); r1 += __shfl_xor(r1, 16); r2 += __shfl_xor(r2, 16);
        r0 += __shfl_xor(r0, 32); r1 += __shfl_xor(r1, 32); r2 += __shfl_xor(r2, 32);
        pk0[kk] = r0; pk1[kk] = r1; pk2[kk] = r2;
    }
    float mx0 = pk0[0], mx1 = pk1[0], mx2 = pk2[0];
    #pragma unroll
    for (int kk = 1; kk < 16; ++kk) {
        mx0 = fmaxf(mx0, pk0[kk]);
        mx1 = fmaxf(mx1, pk1[kk]);
        mx2 = fmaxf(mx2, pk2[kk]);
    }

    if (lane == 0) {
        out[i*3+0] = xyz[i*3+0] + mx0 + b2[0];
        out[i*3+1] = xyz[i*3+1] + mx1 + b2[1];
        out[i*3+2] = xyz[i*3+2] + mx2 + b2[2];
    }
}

// ---------------- launch ----------------

extern "C" void kernel_launch(void* const* d_in, const int* in_sizes, int n_in,
                              void* d_out, int out_size, void* d_ws, size_t ws_size,
                              hipStream_t stream) {
    const float* xyz  = (const float*)d_in[0];
    const float* feat = (const float*)d_in[1];
    const float* W1   = (const float*)d_in[2];
    const float* b1   = (const float*)d_in[3];
    const float* W2   = (const float*)d_in[4];
    const float* b2   = (const float*)d_in[5];
    float* out = (float*)d_out;

    char* ws = (char*)d_ws;
    int*            knn   = (int*)(ws + 0);                   //   524288 B
    float*          stile = (float*)(ws + 524288);            //   163840 B
    __hip_bfloat16* Xb    = (__hip_bfloat16*)(ws + 688128);   //  6815744 B
    __hip_bfloat16* Wpt   = (__hip_bfloat16*)(ws + 7503872);  //   638976 B
    __hip_bfloat16* Ub    = (__hip_bfloat16*)(ws + 8142848);  //  6291456 B
    __hip_bfloat16* Vb    = (__hip_bfloat16*)(ws + 14434304); //  6291456 B
    int*            cut   = (int*)(ws + 20725760);            //     1024 B
    int*            thi   = (int*)(ws + 20726784);            //      128 B
    int*            tlo   = (int*)(ws + 20726912);            //      128 B -> end 20727040

    prep_all     <<<dim3(N + NF + 1),  dim3(128), 0, stream>>>(feat, xyz, W1, Xb, Wpt, cut);
    assign_kernel<<<dim3(N/256),       dim3(256), 0, stream>>>(xyz, cut, tlo, thi, stile);
    knn_kernel   <<<dim3(N/4),         dim3(256), 0, stream>>>(stile, tlo, thi, knn);
    gemm_kernel  <<<dim3(N/64, NF/64), dim3(64),  0, stream>>>(Xb, Wpt, b1, Ub, Vb);
    final_kernel <<<dim3(N/4),         dim3(256), 0, stream>>>(Ub, Vb, knn, xyz, W2, b2, out);
}